// Round 10
// baseline (20817.238 us; speedup 1.0000x reference)
//
#include <hip/hip_runtime.h>
#include <cmath>

#define L_     10
#define R_     64
#define G_     128
#define S_     256
#define MEL_   80
#define NCLS_  256
#define HOP_   64
#define END_   256
#define FRAMES_ 8
#define T_     512

// ---- workspace layout (float offsets) ----
#define COND8_OFF   0                               // 8*1280
#define HIST_OFF    10240                           // layers 1..8: [(j-1)][512][64]
#define MBX_OFF     (HIST_OFF + 8*T_*R_)            // x mailboxes [4][64]
#define MBSK_OFF    (MBX_OFF + 4*R_)                // skip contribs [10][256] (raw v, no bias)
#define MBHID_OFF   (MBSK_OFF + 10*S_)              // C -> D [256]
#define FLAG_OFF    (MBHID_OFF + S_)                // flags, 16 ints apart

#define FID_X1     1     // +(k-1): input x flag of B_k, k=1..4
#define FID_SKIP0  5     // +k: skip flag of stage k, k=0..4
#define FID_HID    10
#define FID_PREV   11
#define FID_CLAIM  12

#define NROLE 7
#define SPIN_CAP (1 << 16)

// ====== r7/r8-proven comm primitives (XCD-0 pinned; returning RMWs at TCC) ==
__device__ __forceinline__ void st_atomic_f(float* p, float v) {
  int old;
  asm volatile("global_atomic_swap %0, %1, %2, off sc0\n\ts_waitcnt vmcnt(0)"
               : "=&v"(old) : "v"(p), "v"(__float_as_int(v)) : "memory");
}
__device__ __forceinline__ void st_atomic_f2(float* p0, float v0, float* p1, float v1) {
  int o0, o1;
  asm volatile("global_atomic_swap %0, %2, %3, off sc0\n\t"
               "global_atomic_swap %1, %4, %5, off sc0\n\t"
               "s_waitcnt vmcnt(0)"
               : "=&v"(o0), "=&v"(o1)
               : "v"(p0), "v"(__float_as_int(v0)), "v"(p1), "v"(__float_as_int(v1))
               : "memory");
}
__device__ __forceinline__ float ld_atomic_f(const float* p) {
  int v;
  asm volatile("global_atomic_add %0, %1, %2, off sc0\n\ts_waitcnt vmcnt(0)"
               : "=&v"(v) : "v"(p), "v"(0) : "memory");
  return __int_as_float(v);
}
__device__ __forceinline__ float2 ld_atomic_f2(const float* p0, const float* p1) {
  int v0, v1;
  asm volatile("global_atomic_add %0, %2, %4, off sc0\n\t"
               "global_atomic_add %1, %3, %4, off sc0\n\t"
               "s_waitcnt vmcnt(0)"
               : "=&v"(v0), "=&v"(v1) : "v"(p0), "v"(p1), "v"(0) : "memory");
  return make_float2(__int_as_float(v0), __int_as_float(v1));
}
__device__ __forceinline__ int flag_poll_atomic(int* p) {
  int v;
  asm volatile("global_atomic_add %0, %1, %2, off sc0\n\ts_waitcnt vmcnt(0)"
               : "=&v"(v) : "v"(p), "v"(0) : "memory");
  return v;
}
// non-returning flag publish: issued strictly after the issuing wave's data
// swaps have EXECUTED at the TCC (their vmcnt(0) already completed), so
// whenever the flag lands, the data is committed.
__device__ __forceinline__ void push_flag(int* p, int v) {
  asm volatile("global_atomic_swap %0, %1, off" :: "v"(p), "v"(v) : "memory");
}
__device__ __forceinline__ void wave_wait_flag(int* p, int want, int lane) {
  int v = 0, n = 0;
  do {
    if (lane == 0) v = flag_poll_atomic(p);
    v = __shfl(v, 0, 64);
    if (v >= want) break;
  } while (++n <= SPIN_CAP);
}
__device__ __forceinline__ int wait_prev_wave(int* p, int want, int lane) {
  int v = 0, n = 0;
  do {
    if (lane == 0) v = flag_poll_atomic(p);
    v = __shfl(v, 0, 64);
    if ((v >> 16) >= want) break;
  } while (++n <= SPIN_CAP);
  return v & 0xffff;
}

// ---- single-chain dot macros: EXACT r8 arithmetic (absmax 0.0 proven).
// DO NOT restructure the fma chains or add orders (1-ulp knife edges).
#define DOTREG(N4, W, V4, ACC) do { \
  _Pragma("unroll") \
  for (int k_ = 0; k_ < (N4); ++k_) { float4 a_ = (V4)[k_]; \
    ACC = fmaf((W)[4*k_+0], a_.x, ACC); ACC = fmaf((W)[4*k_+1], a_.y, ACC); \
    ACC = fmaf((W)[4*k_+2], a_.z, ACC); ACC = fmaf((W)[4*k_+3], a_.w, ACC); } \
} while (0)

#define DOTREG_RELU(N4, W, V4, ACC) do { \
  _Pragma("unroll") \
  for (int k_ = 0; k_ < (N4); ++k_) { float4 a_ = (V4)[k_]; \
    a_.x = fmaxf(a_.x, 0.f); a_.y = fmaxf(a_.y, 0.f); \
    a_.z = fmaxf(a_.z, 0.f); a_.w = fmaxf(a_.w, 0.f); \
    ACC = fmaf((W)[4*k_+0], a_.x, ACC); ACC = fmaf((W)[4*k_+1], a_.y, ACC); \
    ACC = fmaf((W)[4*k_+2], a_.z, ACC); ACC = fmaf((W)[4*k_+3], a_.w, ACC); } \
} while (0)

__global__ void cond_prep_kernel(const float* __restrict__ condW,
                                 const float* __restrict__ y,
                                 float* __restrict__ cond8) {
  int idx = blockIdx.x * blockDim.x + threadIdx.x;
  if (idx >= FRAMES_ * L_ * G_) return;
  int f = idx / (L_ * G_);
  int row = idx - f * (L_ * G_);
  float acc = 0.f;
  for (int m = 0; m < MEL_; ++m)
    acc = fmaf(condW[row * MEL_ + m], y[m * FRAMES_ + f], acc);
  cond8[f * (L_ * G_) + row] = acc;
}

__global__ __launch_bounds__(512, 1) void wavenet_pipe(
    const float* __restrict__ samples,
    const int*   __restrict__ c_ptr,
    const float* __restrict__ emb,
    const float* __restrict__ WVp,
    const float* __restrict__ WVx,
    const float* __restrict__ Wo,
    const float* __restrict__ Wob,
    const float* __restrict__ Wol,
    const float* __restrict__ Wobl,
    const float* __restrict__ e1w,
    const float* __restrict__ e1b,
    const float* __restrict__ e2w,
    const float* __restrict__ e2b,
    float* __restrict__ ws,
    int*   __restrict__ out) {

  const int tid = threadIdx.x;

  float* cond8  = ws + COND8_OFF;
  float* hist   = ws + HIST_OFF;
  float* mbx    = ws + MBX_OFF;
  float* mbsk   = ws + MBSK_OFF;
  float* mbhid  = ws + MBHID_OFF;
  int*   flags  = (int*)(ws + FLAG_OFF);
  int*   fprev  = flags + FID_PREV * 16;

  __shared__ __align__(16) float x_s[R_];
  __shared__ __align__(16) float xb_s[R_];
  __shared__ __align__(16) float z_s[R_];
  __shared__ __align__(16) float zb_s[R_];
  __shared__ __align__(16) float cond_a_s[FRAMES_ * G_];
  __shared__ __align__(16) float cond_b_s[FRAMES_ * G_];
  __shared__ __align__(16) float biasC_s[10 * S_];
  __shared__ __align__(16) float vec_s[S_];
  __shared__ __align__(16) float logits_s[NCLS_];
  __shared__ float wred[4], wsum[4];
  __shared__ int wcand[4];
  __shared__ int role_s;

  // ---- XCD-pinned role claiming (r7-proven) ----
  {
    unsigned xcc;
    asm volatile("s_getreg_b32 %0, hwreg(HW_REG_XCC_ID)" : "=s"(xcc));
    if (tid == 0) {
      int r = -1;
      if (xcc == 0) {
        int c0 = atomicAdd(flags + FID_CLAIM * 16, 1);
        if (c0 < NROLE) r = c0;
      }
      role_s = r;
    }
    __syncthreads();
  }
  const int bid = role_s;
  if (bid < 0) return;

  if (bid < 5) {
    // ============ B_k: layers j_a=2k, j_b=2k+1 (512 threads) ============
    // tid 0..127   : gate threads (both layers), r9-proven fused layout
    // tid 128..191 : residual rows 0..63 of Wo_ja
    // tid 192..255 : residual rows 0..63 of Wo_jb (k<4) + x_out publish wave
    // tid 256..511 : skip rows: ska = Wo_ja row 64+s, skb = Wo_jb row 64+s
    //                (k=4: skb = Wol row s), s = tid-256
    const int k = bid;
    const int j_a = 2 * k, j_b = 2 * k + 1;
    const int dil_a = 1 << j_a, dil_b = 1 << j_b;
    const int gr = tid >> 1, gh = tid & 1;

    float wxa_w[32], wxa_f[32], wxb_w[32], wxb_f[32];
    float ska[64], skb[64], wres[64];
    float bres = 0.f;

    if (tid < 128) {
      const float4* p;
      p = (const float4*)(WVx + ((size_t)(j_a * G_ + gr)) * R_ + gh * 32);
      #pragma unroll
      for (int i = 0; i < 8; ++i) ((float4*)wxa_w)[i] = p[i];
      p = (const float4*)(WVx + ((size_t)(j_a * G_ + gr + 64)) * R_ + gh * 32);
      #pragma unroll
      for (int i = 0; i < 8; ++i) ((float4*)wxa_f)[i] = p[i];
      p = (const float4*)(WVx + ((size_t)(j_b * G_ + gr)) * R_ + gh * 32);
      #pragma unroll
      for (int i = 0; i < 8; ++i) ((float4*)wxb_w)[i] = p[i];
      p = (const float4*)(WVx + ((size_t)(j_b * G_ + gr + 64)) * R_ + gh * 32);
      #pragma unroll
      for (int i = 0; i < 8; ++i) ((float4*)wxb_f)[i] = p[i];
    } else if (tid < 192) {
      const float* q = Wo + ((size_t)(j_a * (R_ + S_) + (tid - 128))) * R_;
      #pragma unroll
      for (int i = 0; i < 64; ++i) wres[i] = q[i];
      bres = Wob[j_a * (R_ + S_) + (tid - 128)];
    } else if (tid < 256) {
      if (k < 4) {
        const float* q = Wo + ((size_t)(j_b * (R_ + S_) + (tid - 192))) * R_;
        #pragma unroll
        for (int i = 0; i < 64; ++i) wres[i] = q[i];
        bres = Wob[j_b * (R_ + S_) + (tid - 192)];
      }
    } else {
      const int s = tid - 256;
      const float* q = Wo + ((size_t)(j_a * (R_ + S_) + 64 + s)) * R_;
      #pragma unroll
      for (int i = 0; i < 64; ++i) ska[i] = q[i];
      const float* r = (k < 4) ? (Wo + ((size_t)(j_b * (R_ + S_) + 64 + s)) * R_)
                               : (Wol + (size_t)s * R_);
      #pragma unroll
      for (int i = 0; i < 64; ++i) skb[i] = r[i];
    }
    for (int i = tid; i < FRAMES_ * G_; i += 512) {
      cond_a_s[i] = cond8[(i >> 7) * (L_ * G_) + j_a * G_ + (i & 127)];
      cond_b_s[i] = cond8[(i >> 7) * (L_ * G_) + j_b * G_ + (i & 127)];
    }
    __syncthreads();
    float pd_aw = 0.f, pd_af = 0.f, pd_bw = 0.f, pd_bf = 0.f;
    if (tid < 128 && gh == 0) {
      pd_aw = cond_a_s[gr]; pd_af = cond_a_s[gr + 64];
      pd_bw = cond_b_s[gr]; pd_bf = cond_b_s[gr + 64];
    }

    float* hist_a = (k > 0) ? (hist + (size_t)(j_a - 1) * T_ * R_) : nullptr;
    float* hist_b = (k < 4) ? (hist + (size_t)(j_b - 1) * T_ * R_) : nullptr;
    float* mbx_in  = mbx + (size_t)(k - 1) * R_;            // k>=1
    float* mbx_out = mbx + (size_t)k * R_;                  // k<4
    float* mbsk_a  = mbsk + (size_t)j_a * S_;
    float* mbsk_b  = mbsk + (size_t)j_b * S_;
    int* inflag  = flags + (FID_X1 + k - 1) * 16;           // k>=1
    int* outflag = flags + (FID_X1 + k) * 16;               // k<4
    int* skflag  = flags + (FID_SKIP0 + k) * 16;

    for (int t = 0; t < T_; ++t) {
      // A: acquire x (wave 0 only)
      if (tid < 64) {
        if (k == 0) {
          int prev = 127;
          if (t > 0) prev = wait_prev_wave(fprev, t, tid);
          if (tid < 16)
            ((float4*)x_s)[tid] = ((const float4*)(emb + (size_t)prev * R_))[tid];
        } else {
          wave_wait_flag(inflag, t + 1, tid);
          x_s[tid] = ld_atomic_f(mbx_in + tid);
        }
      }
      __syncthreads();  // (1)

      // B: gate a + z_a (r9-proven fused layout)
      if (tid < 128) {
        const float4* xs4 = (const float4*)(x_s + gh * 32);
        float vw = 0.f, vf = 0.f;
        DOTREG(8, wxa_w, xs4, vw);
        DOTREG(8, wxa_f, xs4, vf);
        vw += __shfl_down(vw, 1, 2);
        vf += __shfl_down(vf, 1, 2);
        if (gh == 0) {
          float hw = vw + pd_aw, hf = vf + pd_af;
          z_s[gr] = tanhf(hw) * (1.f / (1.f + expf(-hf)));
        }
      }
      if (hist_a && tid >= 240 && tid < 256)
        ((float4*)(hist_a + (size_t)t * R_))[tid - 240] = ((const float4*)x_s)[tid - 240];
      __syncthreads();  // (2)

      // C: residual a (wave 2) + skip-a dots (waves 4-7, off critical path)
      float va = 0.f;
      {
        const float4* z4 = (const float4*)z_s;
        if (tid >= 128 && tid < 192) {
          float v = 0.f;
          DOTREG(16, wres, z4, v);
          xb_s[tid - 128] = x_s[tid - 128] + v + bres;
        } else if (tid >= 256) {
          DOTREG(16, ska, z4, va);
        }
      }
      __syncthreads();  // (3)

      // D: gate b + z_b
      if (tid < 128) {
        const float4* xs4 = (const float4*)(xb_s + gh * 32);
        float vw = 0.f, vf = 0.f;
        DOTREG(8, wxb_w, xs4, vw);
        DOTREG(8, wxb_f, xs4, vf);
        vw += __shfl_down(vw, 1, 2);
        vf += __shfl_down(vf, 1, 2);
        if (gh == 0) {
          float hw = vw + pd_bw, hf = vf + pd_bf;
          zb_s[gr] = tanhf(hw) * (1.f / (1.f + expf(-hf)));
        }
      }
      if (hist_b && tid >= 240 && tid < 256)
        ((float4*)(hist_b + (size_t)t * R_))[tid - 240] = ((const float4*)xb_s)[tid - 240];
      __syncthreads();  // (4)

      // E: residual b + x publish (wave 3, single-wave: no barrier before flag)
      if (k < 4 && tid >= 192 && tid < 256) {
        float v = 0.f;
        const float4* zb4 = (const float4*)zb_s;
        DOTREG(16, wres, zb4, v);
        st_atomic_f(mbx_out + (tid - 192), xb_s[tid - 192] + v + bres);
        // this wave's vmcnt(0) inside st_atomic_f covers all 64 lanes' swaps
        if (tid == 192) push_flag(outflag, t + 1);
      }
      // skip-b dots + skip publish (waves 4-7)
      if (tid >= 256) {
        float vb = 0.f;
        const float4* zb4 = (const float4*)zb_s;
        DOTREG(16, skb, zb4, vb);
        st_atomic_f2(mbsk_a + (tid - 256), va, mbsk_b + (tid - 256), vb);
      }
      __syncthreads();  // (5) all skip swaps executed at TCC
      if (tid == 0) push_flag(skflag, t + 1);

      // F: pd precompute for t+1 (r9-proven, gate threads, off critical path)
      const int tn = t + 1;
      if (tn < T_ && tid < 128) {
        const int f1 = tn >> 6;
        float wpw[32], wpf[32], pa[32];
        {
          const float4* pw = (const float4*)(WVp + ((size_t)(j_a * G_ + gr)) * R_ + gh * 32);
          const float4* pf = (const float4*)(WVp + ((size_t)(j_a * G_ + gr + 64)) * R_ + gh * 32);
          #pragma unroll
          for (int i = 0; i < 8; ++i) { ((float4*)wpw)[i] = pw[i]; ((float4*)wpf)[i] = pf[i]; }
          if (k == 0) {
            #pragma unroll
            for (int i = 0; i < 8; ++i) ((float4*)pa)[i] = ((const float4*)(x_s + gh * 32))[i];
          } else {
            const int tp = tn - dil_a;
            if (tp >= 0) {
              const float4* hp = (const float4*)(hist_a + (size_t)tp * R_ + gh * 32);
              #pragma unroll
              for (int i = 0; i < 8; ++i) ((float4*)pa)[i] = hp[i];
            } else {
              #pragma unroll
              for (int i = 0; i < 32; ++i) pa[i] = 0.f;
            }
          }
          float vw = 0.f, vf = 0.f;
          const float4* pa4 = (const float4*)pa;
          DOTREG(8, wpw, pa4, vw);
          DOTREG(8, wpf, pa4, vf);
          vw += __shfl_down(vw, 1, 2);
          vf += __shfl_down(vf, 1, 2);
          if (gh == 0) {
            pd_aw = vw + cond_a_s[f1 * G_ + gr];
            pd_af = vf + cond_a_s[f1 * G_ + gr + 64];
          }
        }
        if (k < 4) {
          const float4* pw = (const float4*)(WVp + ((size_t)(j_b * G_ + gr)) * R_ + gh * 32);
          const float4* pf = (const float4*)(WVp + ((size_t)(j_b * G_ + gr + 64)) * R_ + gh * 32);
          #pragma unroll
          for (int i = 0; i < 8; ++i) { ((float4*)wpw)[i] = pw[i]; ((float4*)wpf)[i] = pf[i]; }
          const int tp = tn - dil_b;
          if (tp >= 0) {
            const float4* hp = (const float4*)(hist_b + (size_t)tp * R_ + gh * 32);
            #pragma unroll
            for (int i = 0; i < 8; ++i) ((float4*)pa)[i] = hp[i];
          } else {
            #pragma unroll
            for (int i = 0; i < 32; ++i) pa[i] = 0.f;
          }
          float vw = 0.f, vf = 0.f;
          const float4* pa4 = (const float4*)pa;
          DOTREG(8, wpw, pa4, vw);
          DOTREG(8, wpf, pa4, vf);
          vw += __shfl_down(vw, 1, 2);
          vf += __shfl_down(vf, 1, 2);
          if (gh == 0) {
            pd_bw = vw + cond_b_s[f1 * G_ + gr];
            pd_bf = vf + cond_b_s[f1 * G_ + gr + 64];
          }
        } else {
          if (gh == 0) {
            pd_bw = cond_b_s[f1 * G_ + gr];   // layer 9: past always 0 (dil=512)
            pd_bf = cond_b_s[f1 * G_ + gr + 64];
          }
        }
      }
      __syncthreads();  // (6) LDS buffers reusable at t+1
    }

  } else if (bid == 5) {
    // ============ C: skip accumulation (exact j order) + E1 ============
    const int o_loc = tid >> 1, halfc = tid & 1;
    float w[128];
    {
      const float* p = e1w + ((size_t)o_loc) * S_ + halfc * 128;
      #pragma unroll
      for (int i = 0; i < 128; ++i) w[i] = p[i];
    }
    const float bias = e1b[o_loc];
    for (int i = tid; i < 10 * S_; i += 512) {
      int j = i >> 8, s = i & 255;
      biasC_s[i] = (j < 9) ? Wob[j * (R_ + S_) + 64 + s] : Wobl[s];
    }
    int* fhid = flags + FID_HID * 16;
    __syncthreads();

    for (int t = 0; t < T_; ++t) {
      float sacc = 0.f;
      if (tid < 256) {
        const int lane = tid & 63;
        for (int kk = 0; kk < 5; ++kk) {
          wave_wait_flag(flags + (FID_SKIP0 + kk) * 16, t + 1, lane);
          float2 v = ld_atomic_f2(mbsk + (size_t)(2 * kk) * S_ + tid,
                                  mbsk + (size_t)(2 * kk + 1) * S_ + tid);
          sacc = (sacc + v.x) + biasC_s[(2 * kk) * S_ + tid];      // r8 order
          sacc = (sacc + v.y) + biasC_s[(2 * kk + 1) * S_ + tid];
        }
        vec_s[tid] = sacc;
      }
      __syncthreads();
      float v = 0.f;
      const float4* s4 = (const float4*)(vec_s + halfc * 128);
      DOTREG_RELU(32, w, s4, v);
      v += __shfl_down(v, 1, 2);
      if (halfc == 0) st_atomic_f(mbhid + o_loc, fmaxf(v + bias, 0.f));
      __syncthreads();
      if (tid == 0) push_flag(fhid, t + 1);
    }

  } else {
    // ============ D: E2 + sampling (r8-exact) ============
    const int o_loc = tid >> 1, halfc = tid & 1;
    const float cf = (float)c_ptr[0];
    float w[128];
    {
      const float* p = e2w + ((size_t)o_loc) * END_ + halfc * 128;
      #pragma unroll
      for (int i = 0; i < 128; ++i) w[i] = p[i];
    }
    const float bias = e2b[o_loc];
    int* fhid = flags + FID_HID * 16;
    const int lane = tid & 63, wv = tid >> 6;

    for (int t = 0; t < T_; ++t) {
      if (tid < 256) {
        wave_wait_flag(fhid, t + 1, lane);
        vec_s[tid] = ld_atomic_f(mbhid + tid);
      }
      __syncthreads();
      float v = 0.f;
      const float4* h4 = (const float4*)(vec_s + halfc * 128);
      DOTREG(32, w, h4, v);
      v += __shfl_down(v, 1, 2);
      if (halfc == 0) logits_s[o_loc] = (v + bias) * cf;
      __syncthreads();

      // ---- softmax-CDF sampling over 256 logits (r8 verbatim, tid<256) ----
      float lg = 0.f, cs = 0.f;
      if (tid < 256) {
        lg = logits_s[tid];
        float m = lg;
        #pragma unroll
        for (int off = 32; off >= 1; off >>= 1) m = fmaxf(m, __shfl_xor(m, off, 64));
        if (lane == 0) wred[wv] = m;
      }
      __syncthreads();
      if (tid < 256) {
        float m = fmaxf(fmaxf(wred[0], wred[1]), fmaxf(wred[2], wred[3]));
        float e = expf(lg - m);
        cs = e;
        #pragma unroll
        for (int off = 1; off < 64; off <<= 1) {
          float o_ = __shfl_up(cs, off, 64);
          if (lane >= off) cs += o_;
        }
        if (lane == 63) wsum[wv] = cs;
      }
      __syncthreads();
      if (tid < 256) {
        float total = wsum[0] + wsum[1] + wsum[2] + wsum[3];
        float offv = 0.f;
        for (int w2 = 0; w2 < wv; ++w2) offv += wsum[w2];
        float thresh = samples[t] * total;
        bool flagb = (offv + cs) > thresh;
        unsigned long long mk = __ballot(flagb);
        if (lane == 0) wcand[wv] = mk ? (wv * 64 + __ffsll(mk) - 1) : 100000;
      }
      __syncthreads();
      if (tid == 0) {
        int nw = min(min(wcand[0], wcand[1]), min(wcand[2], wcand[3]));
        if (nw >= 100000) nw = 0;  // argmax of all-False -> 0
        out[t] = nw;
        push_flag(fprev, ((t + 1) << 16) | nw);
      }
      __syncthreads();
    }
  }
}

extern "C" void kernel_launch(void* const* d_in, const int* in_sizes, int n_in,
                              void* d_out, int out_size, void* d_ws, size_t ws_size,
                              hipStream_t stream) {
  const float* y       = (const float*)d_in[0];
  const float* samples = (const float*)d_in[1];
  const int*   c       = (const int*)d_in[2];
  const float* emb     = (const float*)d_in[3];
  const float* condW   = (const float*)d_in[4];
  const float* WVp     = (const float*)d_in[5];
  const float* WVx     = (const float*)d_in[6];
  const float* Wo      = (const float*)d_in[7];
  const float* Wob     = (const float*)d_in[8];
  const float* Wol     = (const float*)d_in[9];
  const float* Wobl    = (const float*)d_in[10];
  const float* e1w     = (const float*)d_in[11];
  const float* e1b     = (const float*)d_in[12];
  const float* e2w     = (const float*)d_in[13];
  const float* e2b     = (const float*)d_in[14];

  float* ws  = (float*)d_ws;
  int*   out = (int*)d_out;

  // flags + claim counter must start at 0 every launch (ws re-poisoned to 0xAA)
  hipMemsetAsync((char*)d_ws + (size_t)FLAG_OFF * sizeof(float), 0,
                 16 * 16 * sizeof(int), stream);

  cond_prep_kernel<<<(FRAMES_ * L_ * G_ + 255) / 256, 256, 0, stream>>>(
      condW, y, ws + COND8_OFF);

  wavenet_pipe<<<256, 512, 0, stream>>>(samples, c, emb, WVp, WVx, Wo, Wob,
                                        Wol, Wobl, e1w, e1b, e2w, e2b, ws, out);
}

// Round 11
// 14507.742 us; speedup vs baseline: 1.4349x; 1.4349x over previous
//
#include <hip/hip_runtime.h>
#include <cmath>

#define L_     10
#define R_     64
#define G_     128
#define S_     256
#define MEL_   80
#define NCLS_  256
#define HOP_   64
#define END_   256
#define FRAMES_ 8
#define T_     512

// ---- workspace layout (float offsets) ----
#define COND8_OFF   0                               // 8*1280
#define HIST_OFF    10240                           // layers 1..8: [(j-1)][512][64]
#define MBX_OFF     (HIST_OFF + 8*T_*R_)            // x mailboxes [4][64]
#define MBSK_OFF    (MBX_OFF + 4*R_)                // stage skip mailboxes [4][256]
#define MBSKIP_OFF  (MBSK_OFF + 4*S_)               // B4 -> C [256]
#define MBHID_OFF   (MBSKIP_OFF + S_)               // C -> D [256]
#define FLAG_OFF    (MBHID_OFF + S_)                // flags, 16 ints apart

#define FID_X1     1     // +(k-1): x input flag of B_k, k=1..4
#define FID_SK1    5     // +(k-1): skip input flag of B_k, k=1..4
#define FID_SKIP   9     // B4 -> C
#define FID_HID    10
#define FID_PREV   11
#define FID_CLAIM  12

#define NROLE 7
#define SPIN_CAP (1 << 16)

// ====== r7/r8-proven comm primitives (XCD-0 pinned; returning RMWs at TCC) ==
__device__ __forceinline__ void st_atomic_f(float* p, float v) {
  int old;
  asm volatile("global_atomic_swap %0, %1, %2, off sc0\n\ts_waitcnt vmcnt(0)"
               : "=&v"(old) : "v"(p), "v"(__float_as_int(v)) : "memory");
}
__device__ __forceinline__ void st_atomic_f2(float* p0, float v0, float* p1, float v1) {
  int o0, o1;
  asm volatile("global_atomic_swap %0, %2, %3, off sc0\n\t"
               "global_atomic_swap %1, %4, %5, off sc0\n\t"
               "s_waitcnt vmcnt(0)"
               : "=&v"(o0), "=&v"(o1)
               : "v"(p0), "v"(__float_as_int(v0)), "v"(p1), "v"(__float_as_int(v1))
               : "memory");
}
__device__ __forceinline__ float ld_atomic_f(const float* p) {
  int v;
  asm volatile("global_atomic_add %0, %1, %2, off sc0\n\ts_waitcnt vmcnt(0)"
               : "=&v"(v) : "v"(p), "v"(0) : "memory");
  return __int_as_float(v);
}
__device__ __forceinline__ int flag_poll_atomic(int* p) {
  int v;
  asm volatile("global_atomic_add %0, %1, %2, off sc0\n\ts_waitcnt vmcnt(0)"
               : "=&v"(v) : "v"(p), "v"(0) : "memory");
  return v;
}
// non-returning flag publish; caller guarantees its wave's data swaps have
// already EXECUTED at the TCC (their inline vmcnt(0) completed). r10-proven.
__device__ __forceinline__ void push_flag(int* p, int v) {
  asm volatile("global_atomic_swap %0, %1, off" :: "v"(p), "v"(v) : "memory");
}
__device__ __forceinline__ void wave_wait_flag(int* p, int want, int lane) {
  int v = 0, n = 0;
  do {
    if (lane == 0) v = flag_poll_atomic(p);
    v = __shfl(v, 0, 64);
    if (v >= want) break;
  } while (++n <= SPIN_CAP);
}
__device__ __forceinline__ int wait_prev_wave(int* p, int want, int lane) {
  int v = 0, n = 0;
  do {
    if (lane == 0) v = flag_poll_atomic(p);
    v = __shfl(v, 0, 64);
    if ((v >> 16) >= want) break;
  } while (++n <= SPIN_CAP);
  return v & 0xffff;
}

// ---- single-chain dot macros: EXACT r8/r9 arithmetic (absmax 0.0 proven).
// DO NOT restructure fma chains or add orders (1-ulp knife edges).
#define DOTREG(N4, W, V4, ACC) do { \
  _Pragma("unroll") \
  for (int k_ = 0; k_ < (N4); ++k_) { float4 a_ = (V4)[k_]; \
    ACC = fmaf((W)[4*k_+0], a_.x, ACC); ACC = fmaf((W)[4*k_+1], a_.y, ACC); \
    ACC = fmaf((W)[4*k_+2], a_.z, ACC); ACC = fmaf((W)[4*k_+3], a_.w, ACC); } \
} while (0)

#define DOTREG_RELU(N4, W, V4, ACC) do { \
  _Pragma("unroll") \
  for (int k_ = 0; k_ < (N4); ++k_) { float4 a_ = (V4)[k_]; \
    a_.x = fmaxf(a_.x, 0.f); a_.y = fmaxf(a_.y, 0.f); \
    a_.z = fmaxf(a_.z, 0.f); a_.w = fmaxf(a_.w, 0.f); \
    ACC = fmaf((W)[4*k_+0], a_.x, ACC); ACC = fmaf((W)[4*k_+1], a_.y, ACC); \
    ACC = fmaf((W)[4*k_+2], a_.z, ACC); ACC = fmaf((W)[4*k_+3], a_.w, ACC); } \
} while (0)

__global__ void cond_prep_kernel(const float* __restrict__ condW,
                                 const float* __restrict__ y,
                                 float* __restrict__ cond8) {
  int idx = blockIdx.x * blockDim.x + threadIdx.x;
  if (idx >= FRAMES_ * L_ * G_) return;
  int f = idx / (L_ * G_);
  int row = idx - f * (L_ * G_);
  float acc = 0.f;
  for (int m = 0; m < MEL_; ++m)
    acc = fmaf(condW[row * MEL_ + m], y[m * FRAMES_ + f], acc);
  cond8[f * (L_ * G_) + row] = acc;
}

__global__ __launch_bounds__(256, 1) void wavenet_pipe(
    const float* __restrict__ samples,
    const int*   __restrict__ c_ptr,
    const float* __restrict__ emb,
    const float* __restrict__ WVp,
    const float* __restrict__ WVx,
    const float* __restrict__ Wo,
    const float* __restrict__ Wob,
    const float* __restrict__ Wol,
    const float* __restrict__ Wobl,
    const float* __restrict__ e1w,
    const float* __restrict__ e1b,
    const float* __restrict__ e2w,
    const float* __restrict__ e2b,
    float* __restrict__ ws,
    int*   __restrict__ out) {

  const int tid = threadIdx.x;

  float* cond8  = ws + COND8_OFF;
  float* hist   = ws + HIST_OFF;
  float* mbx    = ws + MBX_OFF;
  float* mbsk   = ws + MBSK_OFF;
  float* mbskip = ws + MBSKIP_OFF;
  float* mbhid  = ws + MBHID_OFF;
  int*   flags  = (int*)(ws + FLAG_OFF);
  int*   fprev  = flags + FID_PREV * 16;

  __shared__ __align__(16) float x_s[R_];
  __shared__ __align__(16) float xb_s[R_];
  __shared__ __align__(16) float z_s[R_];
  __shared__ __align__(16) float zb_s[R_];
  __shared__ __align__(16) float sk_s[S_];
  __shared__ __align__(16) float cond_a_s[FRAMES_ * G_];
  __shared__ __align__(16) float cond_b_s[FRAMES_ * G_];
  __shared__ __align__(16) float vec_s[S_];
  __shared__ __align__(16) float logits_s[NCLS_];
  __shared__ float wred[4], wsum[4];
  __shared__ int wcand[4];
  __shared__ int role_s;

  // ---- XCD-pinned role claiming (r7-proven) ----
  {
    unsigned xcc;
    asm volatile("s_getreg_b32 %0, hwreg(HW_REG_XCC_ID)" : "=s"(xcc));
    if (tid == 0) {
      int r = -1;
      if (xcc == 0) {
        int c0 = atomicAdd(flags + FID_CLAIM * 16, 1);
        if (c0 < NROLE) r = c0;
      }
      role_s = r;
    }
    __syncthreads();
  }
  const int bid = role_s;
  if (bid < 0) return;

  if (bid < 5) {
    // ============ B_k: layers j_a=2k, j_b=2k+1 (r9 structure, r8 comm) ======
    const int k = bid;
    const int j_a = 2 * k, j_b = 2 * k + 1;
    const int dil_a = 1 << j_a, dil_b = 1 << j_b;
    const int gr = tid >> 1, gh = tid & 1;
    const int lane = tid & 63;

    // ---- weights in regs (r9 layout) ----
    float wxa_w[32], wxa_f[32], wxb_w[32], wxb_f[32];
    float woa0[64], wob0[64], wexA[64], wexB[64];
    float ba0, bb0, bexA = 0.f, bexB = 0.f;
    if (tid < 128) {
      const float4* p;
      p = (const float4*)(WVx + ((size_t)(j_a * G_ + gr)) * R_ + gh * 32);
      #pragma unroll
      for (int i = 0; i < 8; ++i) ((float4*)wxa_w)[i] = p[i];
      p = (const float4*)(WVx + ((size_t)(j_a * G_ + gr + 64)) * R_ + gh * 32);
      #pragma unroll
      for (int i = 0; i < 8; ++i) ((float4*)wxa_f)[i] = p[i];
      p = (const float4*)(WVx + ((size_t)(j_b * G_ + gr)) * R_ + gh * 32);
      #pragma unroll
      for (int i = 0; i < 8; ++i) ((float4*)wxb_w)[i] = p[i];
      p = (const float4*)(WVx + ((size_t)(j_b * G_ + gr + 64)) * R_ + gh * 32);
      #pragma unroll
      for (int i = 0; i < 8; ++i) ((float4*)wxb_f)[i] = p[i];
    }
    {
      const float* q = Wo + ((size_t)(j_a * (R_ + S_) + tid)) * R_;
      #pragma unroll
      for (int i = 0; i < 64; ++i) woa0[i] = q[i];
      ba0 = Wob[j_a * (R_ + S_) + tid];
      if (k < 4) {
        q = Wo + ((size_t)(j_b * (R_ + S_) + tid)) * R_;
        #pragma unroll
        for (int i = 0; i < 64; ++i) wob0[i] = q[i];
        bb0 = Wob[j_b * (R_ + S_) + tid];
      } else {
        q = Wol + (size_t)tid * R_;
        #pragma unroll
        for (int i = 0; i < 64; ++i) wob0[i] = q[i];
        bb0 = Wobl[tid];
      }
      if (tid < 64) {
        q = Wo + ((size_t)(j_a * (R_ + S_) + 256 + tid)) * R_;
        #pragma unroll
        for (int i = 0; i < 64; ++i) wexA[i] = q[i];
        bexA = Wob[j_a * (R_ + S_) + 256 + tid];
      } else if (tid < 128 && k < 4) {
        q = Wo + ((size_t)(j_b * (R_ + S_) + 256 + (tid - 64))) * R_;
        #pragma unroll
        for (int i = 0; i < 64; ++i) wexB[i] = q[i];
        bexB = Wob[j_b * (R_ + S_) + 256 + (tid - 64)];
      }
    }
    for (int i = tid; i < FRAMES_ * G_; i += 256) {
      cond_a_s[i] = cond8[(i >> 7) * (L_ * G_) + j_a * G_ + (i & 127)];
      cond_b_s[i] = cond8[(i >> 7) * (L_ * G_) + j_b * G_ + (i & 127)];
    }
    __syncthreads();
    float pd_aw = 0.f, pd_af = 0.f, pd_bw = 0.f, pd_bf = 0.f;
    if (tid < 128 && gh == 0) {
      pd_aw = cond_a_s[gr]; pd_af = cond_a_s[gr + 64];
      pd_bw = cond_b_s[gr]; pd_bf = cond_b_s[gr + 64];
    }

    float* hist_a = (k > 0) ? (hist + (size_t)(j_a - 1) * T_ * R_) : nullptr;
    float* hist_b = (k < 4) ? (hist + (size_t)(j_b - 1) * T_ * R_) : nullptr;
    float* mbx_in   = mbx + (size_t)(k - 1) * R_;          // k>=1
    float* mbx_out  = mbx + (size_t)k * R_;                // k<4
    float* mbsk_in  = mbsk + (size_t)(k - 1) * S_;         // k>=1
    float* mbsk_out = mbsk + (size_t)k * S_;               // k<4
    int* xflag_in   = flags + (FID_X1 + k - 1) * 16;       // k>=1
    int* xflag_out  = flags + (FID_X1 + k) * 16;           // k<4
    int* skflag_in  = flags + (FID_SK1 + k - 1) * 16;      // k>=1
    int* skflag_out = (k < 4) ? (flags + (FID_SK1 + k) * 16)
                              : (flags + FID_SKIP * 16);

    for (int t = 0; t < T_; ++t) {
      // A: acquire x (wave 0 only — x critical path)
      if (tid < 64) {
        if (k == 0) {
          int prev = 127;
          if (t > 0) prev = wait_prev_wave(fprev, t, tid);
          if (tid < 16)
            ((float4*)x_s)[tid] = ((const float4*)(emb + (size_t)prev * R_))[tid];
        } else {
          wave_wait_flag(xflag_in, t + 1, tid);
          x_s[tid] = ld_atomic_f(mbx_in + tid);
        }
      }
      __syncthreads();  // (1) x ready

      // B: gate a + z_a fused (r9-proven layout)
      if (tid < 128) {
        const float4* xs4 = (const float4*)(x_s + gh * 32);
        float vw = 0.f, vf = 0.f;
        DOTREG(8, wxa_w, xs4, vw);
        DOTREG(8, wxa_f, xs4, vf);
        vw += __shfl_down(vw, 1, 2);
        vf += __shfl_down(vf, 1, 2);
        if (gh == 0) {
          float hw = vw + pd_aw, hf = vf + pd_af;
          z_s[gr] = tanhf(hw) * (1.f / (1.f + expf(-hf)));
        }
      }
      if (hist_a && tid >= 240)
        ((float4*)(hist_a + (size_t)t * R_))[tid - 240] = ((const float4*)x_s)[tid - 240];
      __syncthreads();  // (2) z_a ready

      // C: skip-in acquire (deferred — overlaps producer's skip publish)
      float skin = 0.f, skinx = 0.f;
      if (k > 0) {
        wave_wait_flag(skflag_in, t + 1, lane);   // all 4 waves poll
        if (tid < 64) skinx = ld_atomic_f(mbsk_in + 192 + tid);
        else          skin  = ld_atomic_f(mbsk_in + (tid - 64));
      }
      // Wo layer a (r8/r9 rows & add order)
      {
        float v0 = 0.f;
        const float4* z4 = (const float4*)z_s;
        DOTREG(16, woa0, z4, v0);
        if (tid < 64) {
          float v1 = 0.f;
          DOTREG(16, wexA, z4, v1);
          xb_s[tid] = x_s[tid] + v0 + ba0;
          sk_s[192 + tid] = skinx + v1 + bexA;
        } else {
          sk_s[tid - 64] = skin + v0 + ba0;
        }
      }
      __syncthreads();  // (3) xb + sk ready

      // D: gate b + z_b fused
      if (tid < 128) {
        const float4* xs4 = (const float4*)(xb_s + gh * 32);
        float vw = 0.f, vf = 0.f;
        DOTREG(8, wxb_w, xs4, vw);
        DOTREG(8, wxb_f, xs4, vf);
        vw += __shfl_down(vw, 1, 2);
        vf += __shfl_down(vf, 1, 2);
        if (gh == 0) {
          float hw = vw + pd_bw, hf = vf + pd_bf;
          zb_s[gr] = tanhf(hw) * (1.f / (1.f + expf(-hf)));
        }
      }
      if (hist_b && tid >= 240)
        ((float4*)(hist_b + (size_t)t * R_))[tid - 240] = ((const float4*)xb_s)[tid - 240];
      __syncthreads();  // (4) z_b ready

      // E: Wo layer b + publish. x path: wave 0 alone pushes + fires x-flag
      //    (single-wave vmcnt ordering — r10-proven). Skip path: one barrier
      //    later under skflag_out.
      {
        float v0 = 0.f;
        const float4* zb4 = (const float4*)zb_s;
        DOTREG(16, wob0, zb4, v0);
        if (k < 4) {
          if (tid < 64) {
            st_atomic_f(mbx_out + tid, xb_s[tid] + v0 + bb0);
            if (tid == 0) push_flag(xflag_out, t + 1);   // EARLY x flag
          } else if (tid < 128) {
            float v1 = 0.f;
            DOTREG(16, wexB, zb4, v1);
            st_atomic_f2(mbsk_out + (tid - 64), sk_s[tid - 64] + v0 + bb0,
                         mbsk_out + 128 + tid,  sk_s[128 + tid] + v1 + bexB);
          } else {
            st_atomic_f(mbsk_out + (tid - 64), sk_s[tid - 64] + v0 + bb0);
          }
        } else {
          st_atomic_f(mbskip + tid, sk_s[tid] + v0 + bb0);
        }
      }
      __syncthreads();  // (5) all skip swaps executed at TCC
      if (tid == 64) push_flag(skflag_out, t + 1);

      // F: pd precompute for t+1 (r9-proven: register pd, streamed WVp)
      const int tn = t + 1;
      if (tn < T_ && tid < 128) {
        const int f1 = tn >> 6;
        float wpw[32], wpf[32], pa[32];
        {
          const float4* pw = (const float4*)(WVp + ((size_t)(j_a * G_ + gr)) * R_ + gh * 32);
          const float4* pf = (const float4*)(WVp + ((size_t)(j_a * G_ + gr + 64)) * R_ + gh * 32);
          #pragma unroll
          for (int i = 0; i < 8; ++i) { ((float4*)wpw)[i] = pw[i]; ((float4*)wpf)[i] = pf[i]; }
          if (k == 0) {
            #pragma unroll
            for (int i = 0; i < 8; ++i) ((float4*)pa)[i] = ((const float4*)(x_s + gh * 32))[i];
          } else {
            const int tp = tn - dil_a;
            if (tp >= 0) {
              const float4* hp = (const float4*)(hist_a + (size_t)tp * R_ + gh * 32);
              #pragma unroll
              for (int i = 0; i < 8; ++i) ((float4*)pa)[i] = hp[i];
            } else {
              #pragma unroll
              for (int i = 0; i < 32; ++i) pa[i] = 0.f;
            }
          }
          float vw = 0.f, vf = 0.f;
          const float4* pa4 = (const float4*)pa;
          DOTREG(8, wpw, pa4, vw);
          DOTREG(8, wpf, pa4, vf);
          vw += __shfl_down(vw, 1, 2);
          vf += __shfl_down(vf, 1, 2);
          if (gh == 0) {
            pd_aw = vw + cond_a_s[f1 * G_ + gr];
            pd_af = vf + cond_a_s[f1 * G_ + gr + 64];
          }
        }
        if (k < 4) {
          const float4* pw = (const float4*)(WVp + ((size_t)(j_b * G_ + gr)) * R_ + gh * 32);
          const float4* pf = (const float4*)(WVp + ((size_t)(j_b * G_ + gr + 64)) * R_ + gh * 32);
          #pragma unroll
          for (int i = 0; i < 8; ++i) { ((float4*)wpw)[i] = pw[i]; ((float4*)wpf)[i] = pf[i]; }
          const int tp = tn - dil_b;
          if (tp >= 0) {
            const float4* hp = (const float4*)(hist_b + (size_t)tp * R_ + gh * 32);
            #pragma unroll
            for (int i = 0; i < 8; ++i) ((float4*)pa)[i] = hp[i];
          } else {
            #pragma unroll
            for (int i = 0; i < 32; ++i) pa[i] = 0.f;
          }
          float vw = 0.f, vf = 0.f;
          const float4* pa4 = (const float4*)pa;
          DOTREG(8, wpw, pa4, vw);
          DOTREG(8, wpf, pa4, vf);
          vw += __shfl_down(vw, 1, 2);
          vf += __shfl_down(vf, 1, 2);
          if (gh == 0) {
            pd_bw = vw + cond_b_s[f1 * G_ + gr];
            pd_bf = vf + cond_b_s[f1 * G_ + gr + 64];
          }
        } else {
          if (gh == 0) {
            pd_bw = cond_b_s[f1 * G_ + gr];   // layer 9: past always 0 (dil=512)
            pd_bf = cond_b_s[f1 * G_ + gr + 64];
          }
        }
      }
      __syncthreads();  // (6) LDS buffers reusable at t+1
    }

  } else if (bid == 5) {
    // ============ C: E1 (r8-exact) ============
    const int o_loc = tid >> 1, halfc = tid & 1;
    const int lane = tid & 63;
    float w0[128], w1[128];
    {
      const float* p = e1w + ((size_t)o_loc) * S_ + halfc * 128;
      #pragma unroll
      for (int i = 0; i < 128; ++i) w0[i] = p[i];
      p = e1w + ((size_t)(128 + o_loc)) * S_ + halfc * 128;
      #pragma unroll
      for (int i = 0; i < 128; ++i) w1[i] = p[i];
    }
    const float bias0 = e1b[o_loc], bias1 = e1b[128 + o_loc];
    int* inflag  = flags + FID_SKIP * 16;
    int* outflag = flags + FID_HID * 16;

    for (int t = 0; t < T_; ++t) {
      wave_wait_flag(inflag, t + 1, lane);   // all 4 waves poll
      vec_s[tid] = ld_atomic_f(mbskip + tid);
      __syncthreads();
      const float4* s4 = (const float4*)(vec_s + halfc * 128);
      float v0 = 0.f, v1 = 0.f;
      DOTREG_RELU(32, w0, s4, v0);
      v0 += __shfl_down(v0, 1, 2);
      DOTREG_RELU(32, w1, s4, v1);
      v1 += __shfl_down(v1, 1, 2);
      if (halfc == 0)
        st_atomic_f2(mbhid + o_loc,       fmaxf(v0 + bias0, 0.f),
                     mbhid + 128 + o_loc, fmaxf(v1 + bias1, 0.f));
      __syncthreads();
      if (tid == 0) push_flag(outflag, t + 1);
    }

  } else {
    // ============ D: E2 + sampling (r8-exact) ============
    const int o_loc = tid >> 1, halfc = tid & 1;
    const float cf = (float)c_ptr[0];
    float w0[128], w1[128];
    {
      const float* p = e2w + ((size_t)o_loc) * END_ + halfc * 128;
      #pragma unroll
      for (int i = 0; i < 128; ++i) w0[i] = p[i];
      p = e2w + ((size_t)(128 + o_loc)) * END_ + halfc * 128;
      #pragma unroll
      for (int i = 0; i < 128; ++i) w1[i] = p[i];
    }
    const float bias0 = e2b[o_loc], bias1 = e2b[128 + o_loc];
    int* inflag = flags + FID_HID * 16;
    const int lane = tid & 63, wv = tid >> 6;

    for (int t = 0; t < T_; ++t) {
      wave_wait_flag(inflag, t + 1, lane);
      vec_s[tid] = ld_atomic_f(mbhid + tid);
      __syncthreads();
      const float4* h4 = (const float4*)(vec_s + halfc * 128);
      float v0 = 0.f, v1 = 0.f;
      DOTREG(32, w0, h4, v0);
      v0 += __shfl_down(v0, 1, 2);
      DOTREG(32, w1, h4, v1);
      v1 += __shfl_down(v1, 1, 2);
      if (halfc == 0) {
        logits_s[o_loc]       = (v0 + bias0) * cf;
        logits_s[128 + o_loc] = (v1 + bias1) * cf;
      }
      __syncthreads();

      // ---- softmax-CDF sampling over 256 logits (r8 verbatim) ----
      float lg = logits_s[tid];
      float m = lg;
      #pragma unroll
      for (int off = 32; off >= 1; off >>= 1) m = fmaxf(m, __shfl_xor(m, off, 64));
      if (lane == 0) wred[wv] = m;
      __syncthreads();
      m = fmaxf(fmaxf(wred[0], wred[1]), fmaxf(wred[2], wred[3]));
      float e = expf(lg - m);
      float cs = e;
      #pragma unroll
      for (int off = 1; off < 64; off <<= 1) {
        float o_ = __shfl_up(cs, off, 64);
        if (lane >= off) cs += o_;
      }
      if (lane == 63) wsum[wv] = cs;
      __syncthreads();
      float total = wsum[0] + wsum[1] + wsum[2] + wsum[3];
      float offv = 0.f;
      for (int w2 = 0; w2 < wv; ++w2) offv += wsum[w2];
      float thresh = samples[t] * total;
      bool flagb = (offv + cs) > thresh;
      unsigned long long mk = __ballot(flagb);
      if (lane == 0) wcand[wv] = mk ? (wv * 64 + __ffsll(mk) - 1) : 100000;
      __syncthreads();
      if (tid == 0) {
        int nw = min(min(wcand[0], wcand[1]), min(wcand[2], wcand[3]));
        if (nw >= 100000) nw = 0;  // argmax of all-False -> 0
        out[t] = nw;
        push_flag(fprev, ((t + 1) << 16) | nw);
      }
      __syncthreads();  // protect wred/wsum/logits_s before next step
    }
  }
}

extern "C" void kernel_launch(void* const* d_in, const int* in_sizes, int n_in,
                              void* d_out, int out_size, void* d_ws, size_t ws_size,
                              hipStream_t stream) {
  const float* y       = (const float*)d_in[0];
  const float* samples = (const float*)d_in[1];
  const int*   c       = (const int*)d_in[2];
  const float* emb     = (const float*)d_in[3];
  const float* condW   = (const float*)d_in[4];
  const float* WVp     = (const float*)d_in[5];
  const float* WVx     = (const float*)d_in[6];
  const float* Wo      = (const float*)d_in[7];
  const float* Wob     = (const float*)d_in[8];
  const float* Wol     = (const float*)d_in[9];
  const float* Wobl    = (const float*)d_in[10];
  const float* e1w     = (const float*)d_in[11];
  const float* e1b     = (const float*)d_in[12];
  const float* e2w     = (const float*)d_in[13];
  const float* e2b     = (const float*)d_in[14];

  float* ws  = (float*)d_ws;
  int*   out = (int*)d_out;

  // flags + claim counter must start at 0 every launch (ws re-poisoned to 0xAA)
  hipMemsetAsync((char*)d_ws + (size_t)FLAG_OFF * sizeof(float), 0,
                 16 * 16 * sizeof(int), stream);

  cond_prep_kernel<<<(FRAMES_ * L_ * G_ + 255) / 256, 256, 0, stream>>>(
      condW, y, ws + COND8_OFF);

  wavenet_pipe<<<256, 256, 0, stream>>>(samples, c, emb, WVp, WVx, Wo, Wob,
                                        Wol, Wobl, e1w, e1b, e2w, e2b, ws, out);
}

// Round 12
// 13734.259 us; speedup vs baseline: 1.5157x; 1.0563x over previous
//
#include <hip/hip_runtime.h>
#include <cmath>

#define L_     10
#define R_     64
#define G_     128
#define S_     256
#define MEL_   80
#define NCLS_  256
#define HOP_   64
#define END_   256
#define FRAMES_ 8
#define T_     512

// ---- mailbox element stride: 36 floats = 144 B. Contiguous 4 B mailbox
// elements all land in 1-2 TCC channels and atomics SERIALIZE per channel
// (~20-40 cyc each -> ~1 us per 64-elem transfer). 144 B stride (non-pow2)
// spreads consecutive elements across channels for any 128/256 B interleave.
#define MBS 36
#define FLS 36    // flag stride (ints)

// ---- workspace layout (float offsets) ----
#define COND8_OFF   0                                  // 8*1280
#define HIST_OFF    10240                              // layers 1..8: [(j-1)][512][64]
#define MBX_OFF     (HIST_OFF + 8*T_*R_)               // x mailboxes [4][64] strided
#define MBSK_OFF    (MBX_OFF + 4*64*MBS)               // skip mailboxes [4][256] strided
#define MBSKIP_OFF  (MBSK_OFF + 4*256*MBS)             // B4 -> C [256] strided
#define MBHID_OFF   (MBSKIP_OFF + 256*MBS)             // C -> D [256] strided
#define FLAG_OFF    (MBHID_OFF + 256*MBS)              // 16 flags, FLS ints apart

// flag ids: 1..4 = input flag of B1..B4
#define FID_SKIP   5
#define FID_HID    6
#define FID_PREV   7
#define FID_CLAIM  8

#define NROLE 7
#define SPIN_CAP (1 << 16)

// ================= all-RMW comm primitives (XCD-0 pinned, r7/r8-proven) =====
__device__ __forceinline__ void st_atomic_f(float* p, float v) {
  int old;
  asm volatile("global_atomic_swap %0, %1, %2, off sc0\n\ts_waitcnt vmcnt(0)"
               : "=&v"(old) : "v"(p), "v"(__float_as_int(v)) : "memory");
}
__device__ __forceinline__ void st_atomic_f2(float* p0, float v0, float* p1, float v1) {
  int o0, o1;
  asm volatile("global_atomic_swap %0, %2, %3, off sc0\n\t"
               "global_atomic_swap %1, %4, %5, off sc0\n\t"
               "s_waitcnt vmcnt(0)"
               : "=&v"(o0), "=&v"(o1)
               : "v"(p0), "v"(__float_as_int(v0)), "v"(p1), "v"(__float_as_int(v1))
               : "memory");
}
__device__ __forceinline__ float ld_atomic_f(const float* p) {
  int v;
  asm volatile("global_atomic_add %0, %1, %2, off sc0\n\ts_waitcnt vmcnt(0)"
               : "=&v"(v) : "v"(p), "v"(0) : "memory");
  return __int_as_float(v);
}
__device__ __forceinline__ void flag_store_atomic(int* p, int v) {
  int old;
  asm volatile("global_atomic_swap %0, %1, %2, off sc0\n\ts_waitcnt vmcnt(0)"
               : "=&v"(old) : "v"(p), "v"(v) : "memory");
}
__device__ __forceinline__ int flag_poll_atomic(int* p) {
  int v;
  asm volatile("global_atomic_add %0, %1, %2, off sc0\n\ts_waitcnt vmcnt(0)"
               : "=&v"(v) : "v"(p), "v"(0) : "memory");
  return v;
}
__device__ __forceinline__ void wait_flag_wave(int* p, int want, int lane) {
  int v = 0, n = 0;
  do {
    if (lane == 0) v = flag_poll_atomic(p);
    v = __shfl(v, 0, 64);
    if (v >= want) break;
  } while (++n <= SPIN_CAP);
}
__device__ __forceinline__ int wait_prev_wave(int* p, int want, int lane) {
  int v = 0, n = 0;
  do {
    if (lane == 0) v = flag_poll_atomic(p);
    v = __shfl(v, 0, 64);
    if ((v >> 16) >= want) break;
  } while (++n <= SPIN_CAP);
  return v & 0xffff;
}

// ---- single-chain dot macros: EXACT r8 arithmetic (absmax 0.0 proven).
// DO NOT restructure the fma chains or add orders (1-ulp knife edges).
#define DOTREG(N4, W, V4, ACC) do { \
  _Pragma("unroll") \
  for (int k_ = 0; k_ < (N4); ++k_) { float4 a_ = (V4)[k_]; \
    ACC = fmaf((W)[4*k_+0], a_.x, ACC); ACC = fmaf((W)[4*k_+1], a_.y, ACC); \
    ACC = fmaf((W)[4*k_+2], a_.z, ACC); ACC = fmaf((W)[4*k_+3], a_.w, ACC); } \
} while (0)

#define DOTREG_RELU(N4, W, V4, ACC) do { \
  _Pragma("unroll") \
  for (int k_ = 0; k_ < (N4); ++k_) { float4 a_ = (V4)[k_]; \
    a_.x = fmaxf(a_.x, 0.f); a_.y = fmaxf(a_.y, 0.f); \
    a_.z = fmaxf(a_.z, 0.f); a_.w = fmaxf(a_.w, 0.f); \
    ACC = fmaf((W)[4*k_+0], a_.x, ACC); ACC = fmaf((W)[4*k_+1], a_.y, ACC); \
    ACC = fmaf((W)[4*k_+2], a_.z, ACC); ACC = fmaf((W)[4*k_+3], a_.w, ACC); } \
} while (0)

__global__ void cond_prep_kernel(const float* __restrict__ condW,
                                 const float* __restrict__ y,
                                 float* __restrict__ cond8) {
  int idx = blockIdx.x * blockDim.x + threadIdx.x;
  if (idx >= FRAMES_ * L_ * G_) return;
  int f = idx / (L_ * G_);
  int row = idx - f * (L_ * G_);
  float acc = 0.f;
  for (int m = 0; m < MEL_; ++m)
    acc = fmaf(condW[row * MEL_ + m], y[m * FRAMES_ + f], acc);
  cond8[f * (L_ * G_) + row] = acc;
}

__global__ __launch_bounds__(256, 1) void wavenet_pipe(
    const float* __restrict__ samples,
    const int*   __restrict__ c_ptr,
    const float* __restrict__ emb,
    const float* __restrict__ WVp,
    const float* __restrict__ WVx,
    const float* __restrict__ Wo,
    const float* __restrict__ Wob,
    const float* __restrict__ Wol,
    const float* __restrict__ Wobl,
    const float* __restrict__ e1w,
    const float* __restrict__ e1b,
    const float* __restrict__ e2w,
    const float* __restrict__ e2b,
    float* __restrict__ ws,
    int*   __restrict__ out) {

  const int tid = threadIdx.x;

  float* cond8  = ws + COND8_OFF;
  float* hist   = ws + HIST_OFF;
  float* mbxs   = ws + MBX_OFF;
  float* mbsks  = ws + MBSK_OFF;
  float* mbskip = ws + MBSKIP_OFF;
  float* mbhid  = ws + MBHID_OFF;
  int*   flags  = (int*)(ws + FLAG_OFF);

  __shared__ __align__(16) float x_s[R_];
  __shared__ __align__(16) float xb_s[R_];
  __shared__ __align__(16) float h_s[G_];
  __shared__ __align__(16) float z_s[R_];
  __shared__ __align__(16) float pd_a[G_];
  __shared__ __align__(16) float pd_b[G_];
  __shared__ __align__(16) float past_a_s[R_];
  __shared__ __align__(16) float past_b_s[R_];
  __shared__ __align__(16) float sk_s[S_];
  __shared__ __align__(16) float cond_a_s[FRAMES_ * G_];
  __shared__ __align__(16) float cond_b_s[FRAMES_ * G_];  // D reuses as logits
  __shared__ __align__(16) float vec_s[S_];
  __shared__ float wred[4], wsum[4];
  __shared__ int wcand[4];
  __shared__ int role_s;

  // ---- XCD-pinned role claiming (r7-proven): blocks on XCD 0 claim roles.
  {
    unsigned xcc;
    asm volatile("s_getreg_b32 %0, hwreg(HW_REG_XCC_ID)" : "=s"(xcc));
    if (tid == 0) {
      int r = -1;
      if (xcc == 0) {
        int c0 = atomicAdd(flags + FID_CLAIM * FLS, 1);
        if (c0 < NROLE) r = c0;
      }
      role_s = r;
    }
    __syncthreads();
  }
  const int bid = role_s;
  if (bid < 0) return;

  if (bid < 5) {
    // ============ B_k: layers j_a=2k, j_b=2k+1 (r8-exact) ============
    const int k = bid;
    const int j_a = 2 * k, j_b = 2 * k + 1;
    const int dil_a = 1 << j_a, dil_b = 1 << j_b;
    const int row = tid >> 1, half = tid & 1;

    float wxa[32], wpa[32], wxb[32], wpb[32], woa0[64], wob0[64], wex[64];
    float ba0, bb0, bex = 0.f;
    {
      const float* p;
      p = WVx + ((size_t)(j_a * G_ + row)) * R_ + half * 32;
      #pragma unroll
      for (int i = 0; i < 32; ++i) wxa[i] = p[i];
      p = WVp + ((size_t)(j_a * G_ + row)) * R_ + half * 32;
      #pragma unroll
      for (int i = 0; i < 32; ++i) wpa[i] = p[i];
      p = WVx + ((size_t)(j_b * G_ + row)) * R_ + half * 32;
      #pragma unroll
      for (int i = 0; i < 32; ++i) wxb[i] = p[i];
      if (k < 4) {
        p = WVp + ((size_t)(j_b * G_ + row)) * R_ + half * 32;
        #pragma unroll
        for (int i = 0; i < 32; ++i) wpb[i] = p[i];
      }
      p = Wo + ((size_t)(j_a * (R_ + S_) + tid)) * R_;
      #pragma unroll
      for (int i = 0; i < 64; ++i) woa0[i] = p[i];
      ba0 = Wob[j_a * (R_ + S_) + tid];
      if (k < 4) {
        p = Wo + ((size_t)(j_b * (R_ + S_) + tid)) * R_;
        #pragma unroll
        for (int i = 0; i < 64; ++i) wob0[i] = p[i];
        bb0 = Wob[j_b * (R_ + S_) + tid];
      } else {
        p = Wol + (size_t)tid * R_;
        #pragma unroll
        for (int i = 0; i < 64; ++i) wob0[i] = p[i];
        bb0 = Wobl[tid];
      }
      if (tid < 64) {
        p = Wo + ((size_t)(j_a * (R_ + S_) + 256 + tid)) * R_;
        #pragma unroll
        for (int i = 0; i < 64; ++i) wex[i] = p[i];
        bex = Wob[j_a * (R_ + S_) + 256 + tid];
      } else if (tid < 128 && k < 4) {
        p = Wo + ((size_t)(j_b * (R_ + S_) + 256 + (tid - 64))) * R_;
        #pragma unroll
        for (int i = 0; i < 64; ++i) wex[i] = p[i];
        bex = Wob[j_b * (R_ + S_) + 256 + (tid - 64)];
      }
    }
    for (int i = tid; i < FRAMES_ * G_; i += 256) {
      cond_a_s[i] = cond8[(i >> 7) * (L_ * G_) + j_a * G_ + (i & 127)];
      cond_b_s[i] = cond8[(i >> 7) * (L_ * G_) + j_b * G_ + (i & 127)];
    }
    __syncthreads();
    if (tid < G_) { pd_a[tid] = cond_a_s[tid]; pd_b[tid] = cond_b_s[tid]; }

    float* mbx_in   = mbxs + (size_t)(k - 1) * 64 * MBS;   // k>=1
    float* mbsk_in  = mbsks + (size_t)(k - 1) * 256 * MBS;
    float* mbx_out  = mbxs + (size_t)k * 64 * MBS;         // k<4
    float* mbsk_out = mbsks + (size_t)k * 256 * MBS;
    int* inflag   = flags + k * FLS;                       // k>=1
    int* prevflag = flags + FID_PREV * FLS;
    int* outflag  = (k < 4) ? (flags + (k + 1) * FLS) : (flags + FID_SKIP * FLS);
    float* hist_a = (k > 0) ? (hist + (size_t)(j_a - 1) * T_ * R_) : nullptr;
    float* hist_b = (k < 4) ? (hist + (size_t)(j_b - 1) * T_ * R_) : nullptr;

    for (int t = 0; t < T_; ++t) {
      // A: acquire input x
      if (tid < 64) {
        if (k == 0) {
          int prev = 127;
          if (t > 0) prev = wait_prev_wave(prevflag, t, tid);
          if (tid < 16)
            ((float4*)x_s)[tid] = ((const float4*)(emb + (size_t)prev * R_))[tid];
        } else {
          wait_flag_wave(inflag, t + 1, tid);
          x_s[tid] = ld_atomic_f(mbx_in + (size_t)tid * MBS);
        }
      }
      __syncthreads();  // (1)

      // B: gate layer a  (h = pd_a (past-dot + cond, precomputed) + WVx @ x)
      {
        float v = 0.f;
        const float4* xs4 = (const float4*)(x_s + half * 32);
        DOTREG(8, wxa, xs4, v);
        v += __shfl_down(v, 1, 2);
        if (half == 0) h_s[row] = v + pd_a[row];
      }
      if (hist_a && tid < 16)
        ((float4*)(hist_a + (size_t)t * R_))[tid] = ((const float4*)x_s)[tid];
      __syncthreads();  // (2)

      // C: z_a
      if (tid < 64) {
        float hw = h_s[tid], hf = h_s[tid + 64];
        z_s[tid] = tanhf(hw) * (1.f / (1.f + expf(-hf)));
      }
      __syncthreads();  // (3)

      // D: Wo layer a -> xb_s, sk_s  (r8 rows & add order)
      {
        float skin = 0.f;
        if (k > 0) {
          if (tid >= 64) skin = ld_atomic_f(mbsk_in + (size_t)(tid - 64) * MBS);
          else           skin = ld_atomic_f(mbsk_in + (size_t)(192 + tid) * MBS);
        }
        float v0 = 0.f;
        const float4* z4 = (const float4*)z_s;
        DOTREG(16, woa0, z4, v0);
        if (tid < 64) {
          float v1 = 0.f;
          DOTREG(16, wex, z4, v1);
          xb_s[tid] = x_s[tid] + v0 + ba0;
          sk_s[192 + tid] = skin + v1 + bex;
        } else {
          sk_s[tid - 64] = skin + v0 + ba0;
        }
      }
      __syncthreads();  // (4)

      // E: gate layer b
      {
        float v = 0.f;
        const float4* xs4 = (const float4*)(xb_s + half * 32);
        DOTREG(8, wxb, xs4, v);
        v += __shfl_down(v, 1, 2);
        if (half == 0) h_s[row] = v + pd_b[row];
      }
      if (hist_b && tid < 16)
        ((float4*)(hist_b + (size_t)t * R_))[tid] = ((const float4*)xb_s)[tid];
      __syncthreads();  // (5)

      // F: z_b
      if (tid < 64) {
        float hw = h_s[tid], hf = h_s[tid + 64];
        z_s[tid] = tanhf(hw) * (1.f / (1.f + expf(-hf)));
      }
      __syncthreads();  // (6)

      // G: Wo layer b + publish (strided atomic swaps)
      {
        float v0 = 0.f;
        const float4* z4 = (const float4*)z_s;
        DOTREG(16, wob0, z4, v0);
        if (k < 4) {
          if (tid < 64) {
            st_atomic_f(mbx_out + (size_t)tid * MBS, xb_s[tid] + v0 + bb0);
          } else if (tid < 128) {
            float v1 = 0.f;
            DOTREG(16, wex, z4, v1);
            st_atomic_f2(mbsk_out + (size_t)(tid - 64) * MBS, sk_s[tid - 64] + v0 + bb0,
                         mbsk_out + (size_t)(128 + tid) * MBS, sk_s[128 + tid] + v1 + bex);
          } else {
            st_atomic_f(mbsk_out + (size_t)(tid - 64) * MBS, sk_s[tid - 64] + v0 + bb0);
          }
        } else {
          st_atomic_f(mbskip + (size_t)tid * MBS, sk_s[tid] + v0 + bb0);
        }
      }
      __syncthreads();  // (7) every swap has EXECUTED at the TCC
      if (tid == 0) flag_store_atomic(outflag, t + 1);

      // H: off-critical-path: precompute pd_a/pd_b for t+1
      const int tn = t + 1;
      if (tn < T_) {
        const int f1 = tn >> 6;
        if (k > 0 && tid < 16) {
          const int tp = tn - dil_a;
          float4 pv = make_float4(0.f, 0.f, 0.f, 0.f);
          if (tp >= 0) pv = ((const float4*)(hist_a + (size_t)tp * R_))[tid];
          ((float4*)past_a_s)[tid] = pv;
        }
        if (k < 4 && tid >= 16 && tid < 32) {
          const int tp = tn - dil_b;
          float4 pv = make_float4(0.f, 0.f, 0.f, 0.f);
          if (tp >= 0) pv = ((const float4*)(hist_b + (size_t)tp * R_))[tid - 16];
          ((float4*)past_b_s)[tid - 16] = pv;
        }
        __syncthreads();  // (8)
        {
          float v = 0.f;
          const float4* ps4 = (k == 0) ? (const float4*)(x_s + half * 32)
                                       : (const float4*)(past_a_s + half * 32);
          DOTREG(8, wpa, ps4, v);
          v += __shfl_down(v, 1, 2);
          if (half == 0) pd_a[row] = v + cond_a_s[f1 * G_ + row];
        }
        if (k < 4) {
          float v = 0.f;
          const float4* ps4 = (const float4*)(past_b_s + half * 32);
          DOTREG(8, wpb, ps4, v);
          v += __shfl_down(v, 1, 2);
          if (half == 0) pd_b[row] = v + cond_b_s[f1 * G_ + row];
        } else {
          if (tid < G_) pd_b[tid] = cond_b_s[f1 * G_ + tid];  // layer 9: past always 0
        }
      }
      __syncthreads();  // (9) pd/x_s writes ordered before next-iter overwrite
    }

  } else if (bid == 5) {
    // ============ C: full E1 (r8-exact) ============
    const int o_loc = tid >> 1, halfc = tid & 1;
    float w0[128], w1[128];
    {
      const float* p = e1w + ((size_t)o_loc) * S_ + halfc * 128;
      #pragma unroll
      for (int i = 0; i < 128; ++i) w0[i] = p[i];
      p = e1w + ((size_t)(128 + o_loc)) * S_ + halfc * 128;
      #pragma unroll
      for (int i = 0; i < 128; ++i) w1[i] = p[i];
    }
    const float bias0 = e1b[o_loc], bias1 = e1b[128 + o_loc];
    int* inflag  = flags + FID_SKIP * FLS;
    int* outflag = flags + FID_HID * FLS;

    for (int t = 0; t < T_; ++t) {
      if (tid < 64) wait_flag_wave(inflag, t + 1, tid);
      __syncthreads();
      vec_s[tid] = ld_atomic_f(mbskip + (size_t)tid * MBS);
      __syncthreads();
      const float4* s4 = (const float4*)(vec_s + halfc * 128);
      float v0 = 0.f, v1 = 0.f;
      DOTREG_RELU(32, w0, s4, v0);
      v0 += __shfl_down(v0, 1, 2);
      DOTREG_RELU(32, w1, s4, v1);
      v1 += __shfl_down(v1, 1, 2);
      if (halfc == 0)
        st_atomic_f2(mbhid + (size_t)o_loc * MBS,       fmaxf(v0 + bias0, 0.f),
                     mbhid + (size_t)(128 + o_loc) * MBS, fmaxf(v1 + bias1, 0.f));
      __syncthreads();
      if (tid == 0) flag_store_atomic(outflag, t + 1);
    }

  } else {
    // ============ D: full E2 + sampling (r8-exact) ============
    const int o_loc = tid >> 1, halfc = tid & 1;
    const float cf = (float)c_ptr[0];
    float w0[128], w1[128];
    {
      const float* p = e2w + ((size_t)o_loc) * END_ + halfc * 128;
      #pragma unroll
      for (int i = 0; i < 128; ++i) w0[i] = p[i];
      p = e2w + ((size_t)(128 + o_loc)) * END_ + halfc * 128;
      #pragma unroll
      for (int i = 0; i < 128; ++i) w1[i] = p[i];
    }
    const float bias0 = e2b[o_loc], bias1 = e2b[128 + o_loc];
    int* inflag = flags + FID_HID * FLS;
    int* fprev  = flags + FID_PREV * FLS;
    float* logits_s = cond_b_s;  // reuse (unused by D)
    const int lane = tid & 63, wv = tid >> 6;

    for (int t = 0; t < T_; ++t) {
      if (tid < 64) wait_flag_wave(inflag, t + 1, tid);
      __syncthreads();
      vec_s[tid] = ld_atomic_f(mbhid + (size_t)tid * MBS);
      __syncthreads();
      const float4* h4 = (const float4*)(vec_s + halfc * 128);
      float v0 = 0.f, v1 = 0.f;
      DOTREG(32, w0, h4, v0);
      v0 += __shfl_down(v0, 1, 2);
      DOTREG(32, w1, h4, v1);
      v1 += __shfl_down(v1, 1, 2);
      if (halfc == 0) {
        logits_s[o_loc]       = (v0 + bias0) * cf;
        logits_s[128 + o_loc] = (v1 + bias1) * cf;
      }
      __syncthreads();

      // ---- softmax-CDF sampling over 256 logits (r8 verbatim) ----
      float lg = logits_s[tid];
      float m = lg;
      #pragma unroll
      for (int off = 32; off >= 1; off >>= 1) m = fmaxf(m, __shfl_xor(m, off, 64));
      if (lane == 0) wred[wv] = m;
      __syncthreads();
      m = fmaxf(fmaxf(wred[0], wred[1]), fmaxf(wred[2], wred[3]));
      float e = expf(lg - m);
      float cs = e;
      #pragma unroll
      for (int off = 1; off < 64; off <<= 1) {
        float o_ = __shfl_up(cs, off, 64);
        if (lane >= off) cs += o_;
      }
      if (lane == 63) wsum[wv] = cs;
      __syncthreads();
      float total = wsum[0] + wsum[1] + wsum[2] + wsum[3];
      float offv = 0.f;
      for (int w2 = 0; w2 < wv; ++w2) offv += wsum[w2];
      float thresh = samples[t] * total;
      bool flagb = (offv + cs) > thresh;
      unsigned long long mk = __ballot(flagb);
      if (lane == 0) wcand[wv] = mk ? (wv * 64 + __ffsll(mk) - 1) : 100000;
      __syncthreads();
      if (tid == 0) {
        int nw = min(min(wcand[0], wcand[1]), min(wcand[2], wcand[3]));
        if (nw >= 100000) nw = 0;  // argmax of all-False -> 0
        out[t] = nw;
        flag_store_atomic(fprev, ((t + 1) << 16) | nw);
      }
      __syncthreads();  // protect wred/wsum/logits_s before next step
    }
  }
}

extern "C" void kernel_launch(void* const* d_in, const int* in_sizes, int n_in,
                              void* d_out, int out_size, void* d_ws, size_t ws_size,
                              hipStream_t stream) {
  const float* y       = (const float*)d_in[0];
  const float* samples = (const float*)d_in[1];
  const int*   c       = (const int*)d_in[2];
  const float* emb     = (const float*)d_in[3];
  const float* condW   = (const float*)d_in[4];
  const float* WVp     = (const float*)d_in[5];
  const float* WVx     = (const float*)d_in[6];
  const float* Wo      = (const float*)d_in[7];
  const float* Wob     = (const float*)d_in[8];
  const float* Wol     = (const float*)d_in[9];
  const float* Wobl    = (const float*)d_in[10];
  const float* e1w     = (const float*)d_in[11];
  const float* e1b     = (const float*)d_in[12];
  const float* e2w     = (const float*)d_in[13];
  const float* e2b     = (const float*)d_in[14];

  float* ws  = (float*)d_ws;
  int*   out = (int*)d_out;

  // flags + claim counter must start at 0 every launch (ws re-poisoned to 0xAA)
  hipMemsetAsync((char*)d_ws + (size_t)FLAG_OFF * sizeof(float), 0,
                 16 * FLS * sizeof(int), stream);

  cond_prep_kernel<<<(FRAMES_ * L_ * G_ + 255) / 256, 256, 0, stream>>>(
      condW, y, ws + COND8_OFF);

  wavenet_pipe<<<256, 256, 0, stream>>>(samples, c, emb, WVp, WVx, Wo, Wob,
                                        Wol, Wobl, e1w, e1b, e2w, e2b, ws, out);
}

// Round 13
// 11107.392 us; speedup vs baseline: 1.8742x; 1.2365x over previous
//
#include <hip/hip_runtime.h>
#include <cmath>

#define L_     10
#define R_     64
#define G_     128
#define S_     256
#define MEL_   80
#define NCLS_  256
#define HOP_   64
#define END_   256
#define FRAMES_ 8
#define T_     512

// ---- workspace layout (float offsets) ----
#define COND8_OFF   0                                // 8*1280
#define HIST_OFF    10240                            // layers 1..8: [(j-1)][512][64]
#define MBX_OFF     (HIST_OFF + 8*T_*R_)             // x mailboxes [4][64]
#define CONTRIB_OFF (MBX_OFF + 4*R_)                 // raw skip contribs [10][256]
#define MBHID_OFF   (CONTRIB_OFF + 10*S_)            // C -> D [256]
#define FLAG_OFF    (MBHID_OFF + S_)                 // flags, 16 ints apart

#define FID_X1     1     // +(k-1): x input flag of B_k, k=1..4
#define FID_SK0    5     // +k: contribution flag of stage k, k=0..4
#define FID_HID    10
#define FID_PREV   11
#define FID_CLAIM  12

#define NROLE 7
#define SPIN_CAP (1 << 16)

// ====== r7/r8-proven comm primitives (XCD-0 pinned; returning RMWs at TCC) ==
__device__ __forceinline__ void st_atomic_f(float* p, float v) {
  int old;
  asm volatile("global_atomic_swap %0, %1, %2, off sc0\n\ts_waitcnt vmcnt(0)"
               : "=&v"(old) : "v"(p), "v"(__float_as_int(v)) : "memory");
}
__device__ __forceinline__ void st_atomic_f2(float* p0, float v0, float* p1, float v1) {
  int o0, o1;
  asm volatile("global_atomic_swap %0, %2, %3, off sc0\n\t"
               "global_atomic_swap %1, %4, %5, off sc0\n\t"
               "s_waitcnt vmcnt(0)"
               : "=&v"(o0), "=&v"(o1)
               : "v"(p0), "v"(__float_as_int(v0)), "v"(p1), "v"(__float_as_int(v1))
               : "memory");
}
__device__ __forceinline__ float ld_atomic_f(const float* p) {
  int v;
  asm volatile("global_atomic_add %0, %1, %2, off sc0\n\ts_waitcnt vmcnt(0)"
               : "=&v"(v) : "v"(p), "v"(0) : "memory");
  return __int_as_float(v);
}
__device__ __forceinline__ float2 ld_atomic_f2(const float* p0, const float* p1) {
  int v0, v1;
  asm volatile("global_atomic_add %0, %2, %4, off sc0\n\t"
               "global_atomic_add %1, %3, %4, off sc0\n\t"
               "s_waitcnt vmcnt(0)"
               : "=&v"(v0), "=&v"(v1) : "v"(p0), "v"(p1), "v"(0) : "memory");
  return make_float2(__int_as_float(v0), __int_as_float(v1));
}
__device__ __forceinline__ int flag_poll_atomic(int* p) {
  int v;
  asm volatile("global_atomic_add %0, %1, %2, off sc0\n\ts_waitcnt vmcnt(0)"
               : "=&v"(v) : "v"(p), "v"(0) : "memory");
  return v;
}
// non-returning flag publish; issued only after the issuing WAVE's data swaps
// completed their wave-level vmcnt(0) => data committed at TCC first.
// (vmcnt is per-wave and covers all 64 lanes' swaps — r10/r11-proven.)
__device__ __forceinline__ void push_flag(int* p, int v) {
  asm volatile("global_atomic_swap %0, %1, off" :: "v"(p), "v"(v) : "memory");
}
__device__ __forceinline__ void wave_wait_flag(int* p, int want, int lane) {
  int v = 0, n = 0;
  do {
    if (lane == 0) v = flag_poll_atomic(p);
    v = __shfl(v, 0, 64);
    if (v >= want) break;
  } while (++n <= SPIN_CAP);
}
__device__ __forceinline__ int wait_prev_wave(int* p, int want, int lane) {
  int v = 0, n = 0;
  do {
    if (lane == 0) v = flag_poll_atomic(p);
    v = __shfl(v, 0, 64);
    if ((v >> 16) >= want) break;
  } while (++n <= SPIN_CAP);
  return v & 0xffff;
}

// ---- single-chain dot macros: EXACT r8 arithmetic (absmax 0.0 proven).
// DO NOT restructure the fma chains or add orders (1-ulp knife edges).
#define DOTREG(N4, W, V4, ACC) do { \
  _Pragma("unroll") \
  for (int k_ = 0; k_ < (N4); ++k_) { float4 a_ = (V4)[k_]; \
    ACC = fmaf((W)[4*k_+0], a_.x, ACC); ACC = fmaf((W)[4*k_+1], a_.y, ACC); \
    ACC = fmaf((W)[4*k_+2], a_.z, ACC); ACC = fmaf((W)[4*k_+3], a_.w, ACC); } \
} while (0)

#define DOTREG_RELU(N4, W, V4, ACC) do { \
  _Pragma("unroll") \
  for (int k_ = 0; k_ < (N4); ++k_) { float4 a_ = (V4)[k_]; \
    a_.x = fmaxf(a_.x, 0.f); a_.y = fmaxf(a_.y, 0.f); \
    a_.z = fmaxf(a_.z, 0.f); a_.w = fmaxf(a_.w, 0.f); \
    ACC = fmaf((W)[4*k_+0], a_.x, ACC); ACC = fmaf((W)[4*k_+1], a_.y, ACC); \
    ACC = fmaf((W)[4*k_+2], a_.z, ACC); ACC = fmaf((W)[4*k_+3], a_.w, ACC); } \
} while (0)

__global__ void cond_prep_kernel(const float* __restrict__ condW,
                                 const float* __restrict__ y,
                                 float* __restrict__ cond8) {
  int idx = blockIdx.x * blockDim.x + threadIdx.x;
  if (idx >= FRAMES_ * L_ * G_) return;
  int f = idx / (L_ * G_);
  int row = idx - f * (L_ * G_);
  float acc = 0.f;
  for (int m = 0; m < MEL_; ++m)
    acc = fmaf(condW[row * MEL_ + m], y[m * FRAMES_ + f], acc);
  cond8[f * (L_ * G_) + row] = acc;
}

__global__ __launch_bounds__(256, 1) void wavenet_pipe(
    const float* __restrict__ samples,
    const int*   __restrict__ c_ptr,
    const float* __restrict__ emb,
    const float* __restrict__ WVp,
    const float* __restrict__ WVx,
    const float* __restrict__ Wo,
    const float* __restrict__ Wob,
    const float* __restrict__ Wol,
    const float* __restrict__ Wobl,
    const float* __restrict__ e1w,
    const float* __restrict__ e1b,
    const float* __restrict__ e2w,
    const float* __restrict__ e2b,
    float* __restrict__ ws,
    int*   __restrict__ out) {

  const int tid = threadIdx.x;

  float* cond8   = ws + COND8_OFF;
  float* hist    = ws + HIST_OFF;
  float* mbx     = ws + MBX_OFF;
  float* contrib = ws + CONTRIB_OFF;
  float* mbhid   = ws + MBHID_OFF;
  int*   flags   = (int*)(ws + FLAG_OFF);
  int*   fprev   = flags + FID_PREV * 16;

  __shared__ __align__(16) float x_s[R_];
  __shared__ __align__(16) float xb_s[R_];
  __shared__ __align__(16) float h_s[G_];
  __shared__ __align__(16) float z_s[R_];
  __shared__ __align__(16) float pd_a[G_];
  __shared__ __align__(16) float pd_b[G_];
  __shared__ __align__(16) float past_a_s[R_];
  __shared__ __align__(16) float past_b_s[R_];
  __shared__ __align__(16) float cond_a_s[FRAMES_ * G_];
  __shared__ __align__(16) float cond_b_s[FRAMES_ * G_];  // D reuses as logits
  __shared__ __align__(16) float biasC_s[10 * S_];        // C only
  __shared__ __align__(16) float vec_s[S_];
  __shared__ float wred[4], wsum[4];
  __shared__ int wcand[4];
  __shared__ int role_s;

  // ---- XCD-pinned role claiming (r7-proven) ----
  {
    unsigned xcc;
    asm volatile("s_getreg_b32 %0, hwreg(HW_REG_XCC_ID)" : "=s"(xcc));
    if (tid == 0) {
      int r = -1;
      if (xcc == 0) {
        int c0 = atomicAdd(flags + FID_CLAIM * 16, 1);
        if (c0 < NROLE) r = c0;
      }
      role_s = r;
    }
    __syncthreads();
  }
  const int bid = role_s;
  if (bid < 0) return;

  if (bid < 5) {
    // ============ B_k: layers j_a=2k, j_b=2k+1 (r8 chassis, skip offloaded) ==
    const int k = bid;
    const int j_a = 2 * k, j_b = 2 * k + 1;
    const int dil_a = 1 << j_a, dil_b = 1 << j_b;
    const int row = tid >> 1, half = tid & 1;

    float wxa[32], wpa[32], wxb[32], wpb[32], woa0[64], wob0[64], wex[64];
    float ba0, bb0;
    {
      const float* p;
      p = WVx + ((size_t)(j_a * G_ + row)) * R_ + half * 32;
      #pragma unroll
      for (int i = 0; i < 32; ++i) wxa[i] = p[i];
      p = WVp + ((size_t)(j_a * G_ + row)) * R_ + half * 32;
      #pragma unroll
      for (int i = 0; i < 32; ++i) wpa[i] = p[i];
      p = WVx + ((size_t)(j_b * G_ + row)) * R_ + half * 32;
      #pragma unroll
      for (int i = 0; i < 32; ++i) wxb[i] = p[i];
      if (k < 4) {
        p = WVp + ((size_t)(j_b * G_ + row)) * R_ + half * 32;
        #pragma unroll
        for (int i = 0; i < 32; ++i) wpb[i] = p[i];
      }
      p = Wo + ((size_t)(j_a * (R_ + S_) + tid)) * R_;
      #pragma unroll
      for (int i = 0; i < 64; ++i) woa0[i] = p[i];
      ba0 = Wob[j_a * (R_ + S_) + tid];
      if (k < 4) {
        p = Wo + ((size_t)(j_b * (R_ + S_) + tid)) * R_;
        #pragma unroll
        for (int i = 0; i < 64; ++i) wob0[i] = p[i];
        bb0 = Wob[j_b * (R_ + S_) + tid];
      } else {
        p = Wol + (size_t)tid * R_;
        #pragma unroll
        for (int i = 0; i < 64; ++i) wob0[i] = p[i];
        bb0 = Wobl[tid];   // unused (bias applied at C for layer 9)
      }
      if (tid < 64) {
        p = Wo + ((size_t)(j_a * (R_ + S_) + 256 + tid)) * R_;
        #pragma unroll
        for (int i = 0; i < 64; ++i) wex[i] = p[i];
      } else if (tid < 128 && k < 4) {
        p = Wo + ((size_t)(j_b * (R_ + S_) + 256 + (tid - 64))) * R_;
        #pragma unroll
        for (int i = 0; i < 64; ++i) wex[i] = p[i];
      }
    }
    for (int i = tid; i < FRAMES_ * G_; i += 256) {
      cond_a_s[i] = cond8[(i >> 7) * (L_ * G_) + j_a * G_ + (i & 127)];
      cond_b_s[i] = cond8[(i >> 7) * (L_ * G_) + j_b * G_ + (i & 127)];
    }
    __syncthreads();
    if (tid < G_) { pd_a[tid] = cond_a_s[tid]; pd_b[tid] = cond_b_s[tid]; }

    float* mbx_in    = mbx + (size_t)(k - 1) * R_;            // k>=1
    float* mbx_out   = mbx + (size_t)k * R_;                  // k<4
    float* contrib_a = contrib + (size_t)j_a * S_;
    float* contrib_b = contrib + (size_t)j_b * S_;
    int* xflag_in  = flags + (FID_X1 + k - 1) * 16;           // k>=1
    int* xflag_out = flags + (FID_X1 + k) * 16;               // k<4
    int* skflag    = flags + (FID_SK0 + k) * 16;
    float* hist_a = (k > 0) ? (hist + (size_t)(j_a - 1) * T_ * R_) : nullptr;
    float* hist_b = (k < 4) ? (hist + (size_t)(j_b - 1) * T_ * R_) : nullptr;

    for (int t = 0; t < T_; ++t) {
      // A: acquire input x (r8 verbatim)
      if (tid < 64) {
        if (k == 0) {
          int prev = 127;
          if (t > 0) prev = wait_prev_wave(fprev, t, tid);
          if (tid < 16)
            ((float4*)x_s)[tid] = ((const float4*)(emb + (size_t)prev * R_))[tid];
        } else {
          wave_wait_flag(xflag_in, t + 1, tid);
          x_s[tid] = ld_atomic_f(mbx_in + tid);
        }
      }
      __syncthreads();  // (1)

      // B: gate layer a (r8 verbatim)
      {
        float v = 0.f;
        const float4* xs4 = (const float4*)(x_s + half * 32);
        DOTREG(8, wxa, xs4, v);
        v += __shfl_down(v, 1, 2);
        if (half == 0) h_s[row] = v + pd_a[row];
      }
      if (hist_a && tid < 16)
        ((float4*)(hist_a + (size_t)t * R_))[tid] = ((const float4*)x_s)[tid];
      __syncthreads();  // (2)

      // C: z_a (r8 verbatim)
      if (tid < 64) {
        float hw = h_s[tid], hf = h_s[tid + 64];
        z_s[tid] = tanhf(hw) * (1.f / (1.f + expf(-hf)));
      }
      __syncthreads();  // (3)

      // D: Wo layer a — residual only on the fast path; raw skip contribution
      //    held in a register, published in phase G (off the x path).
      float va_keep = 0.f;
      {
        float v0 = 0.f;
        const float4* z4 = (const float4*)z_s;
        DOTREG(16, woa0, z4, v0);
        if (tid < 64) {
          float v1 = 0.f;
          DOTREG(16, wex, z4, v1);
          xb_s[tid] = x_s[tid] + v0 + ba0;   // r8-exact residual
          va_keep = v1;                      // contrib_a row 192+tid (raw)
        } else {
          va_keep = v0;                      // contrib_a row tid-64 (raw)
        }
      }
      __syncthreads();  // (4)

      // E: gate layer b (r8 verbatim)
      {
        float v = 0.f;
        const float4* xs4 = (const float4*)(xb_s + half * 32);
        DOTREG(8, wxb, xs4, v);
        v += __shfl_down(v, 1, 2);
        if (half == 0) h_s[row] = v + pd_b[row];
      }
      if (hist_b && tid < 16)
        ((float4*)(hist_b + (size_t)t * R_))[tid] = ((const float4*)xb_s)[tid];
      __syncthreads();  // (5)

      // F: z_b (r8 verbatim)
      if (tid < 64) {
        float hw = h_s[tid], hf = h_s[tid + 64];
        z_s[tid] = tanhf(hw) * (1.f / (1.f + expf(-hf)));
      }
      __syncthreads();  // (6)

      // G: Wo layer b + publish. x: wave 0 pushes + fires x-flag after its
      //    wave-level vmcnt (EARLY — no barrier). Raw contributions follow.
      {
        float v0 = 0.f;
        const float4* z4 = (const float4*)z_s;
        DOTREG(16, wob0, z4, v0);
        if (k < 4) {
          if (tid < 64) {
            st_atomic_f(mbx_out + tid, xb_s[tid] + v0 + bb0);
            if (tid == 0) push_flag(xflag_out, t + 1);   // EARLY x flag
            st_atomic_f(contrib_a + 192 + tid, va_keep);
          } else if (tid < 128) {
            float v1 = 0.f;
            DOTREG(16, wex, z4, v1);
            st_atomic_f2(contrib_a + (tid - 64), va_keep,
                         contrib_b + (tid - 64), v0);
            st_atomic_f(contrib_b + 192 + (tid - 64), v1);
          } else {
            st_atomic_f2(contrib_a + (tid - 64), va_keep,
                         contrib_b + (tid - 64), v0);
          }
        } else {
          // layer 9: all 256 rows are contributions (bias at C)
          if (tid < 64) {
            st_atomic_f2(contrib_b + tid, v0, contrib_a + 192 + tid, va_keep);
          } else {
            st_atomic_f2(contrib_a + (tid - 64), va_keep, contrib_b + tid, v0);
          }
        }
      }
      __syncthreads();  // (7) all contribution swaps executed at the TCC
      if (tid == 0) push_flag(skflag, t + 1);

      // H: off-critical-path: precompute pd_a/pd_b for t+1 (r8 verbatim)
      const int tn = t + 1;
      if (tn < T_) {
        const int f1 = tn >> 6;
        if (k > 0 && tid < 16) {
          const int tp = tn - dil_a;
          float4 pv = make_float4(0.f, 0.f, 0.f, 0.f);
          if (tp >= 0) pv = ((const float4*)(hist_a + (size_t)tp * R_))[tid];
          ((float4*)past_a_s)[tid] = pv;
        }
        if (k < 4 && tid >= 16 && tid < 32) {
          const int tp = tn - dil_b;
          float4 pv = make_float4(0.f, 0.f, 0.f, 0.f);
          if (tp >= 0) pv = ((const float4*)(hist_b + (size_t)tp * R_))[tid - 16];
          ((float4*)past_b_s)[tid - 16] = pv;
        }
        __syncthreads();  // (8)
        {
          float v = 0.f;
          const float4* ps4 = (k == 0) ? (const float4*)(x_s + half * 32)
                                       : (const float4*)(past_a_s + half * 32);
          DOTREG(8, wpa, ps4, v);
          v += __shfl_down(v, 1, 2);
          if (half == 0) pd_a[row] = v + cond_a_s[f1 * G_ + row];
        }
        if (k < 4) {
          float v = 0.f;
          const float4* ps4 = (const float4*)(past_b_s + half * 32);
          DOTREG(8, wpb, ps4, v);
          v += __shfl_down(v, 1, 2);
          if (half == 0) pd_b[row] = v + cond_b_s[f1 * G_ + row];
        } else {
          if (tid < G_) pd_b[tid] = cond_b_s[f1 * G_ + tid];  // layer 9: past always 0
        }
      }
      __syncthreads();  // (9) pd/x_s writes ordered before next-iter overwrite
    }

  } else if (bid == 5) {
    // ============ C: ordered skip fold (r10-proven) + E1 (r8-exact) ============
    const int o_loc = tid >> 1, halfc = tid & 1;
    const int lane = tid & 63;
    float w0[128], w1[128];
    {
      const float* p = e1w + ((size_t)o_loc) * S_ + halfc * 128;
      #pragma unroll
      for (int i = 0; i < 128; ++i) w0[i] = p[i];
      p = e1w + ((size_t)(128 + o_loc)) * S_ + halfc * 128;
      #pragma unroll
      for (int i = 0; i < 128; ++i) w1[i] = p[i];
    }
    const float bias0 = e1b[o_loc], bias1 = e1b[128 + o_loc];
    for (int i = tid; i < 10 * S_; i += 256) {
      int j = i >> 8, s = i & 255;
      biasC_s[i] = (j < 9) ? Wob[j * (R_ + S_) + 64 + s] : Wobl[s];
    }
    int* outflag = flags + FID_HID * 16;
    __syncthreads();

    for (int t = 0; t < T_; ++t) {
      // fold contributions in exact layer order: s = (s + v_j) + b_j
      float sacc = 0.f;
      for (int kk = 0; kk < 5; ++kk) {
        wave_wait_flag(flags + (FID_SK0 + kk) * 16, t + 1, lane);
        float2 v = ld_atomic_f2(contrib + (size_t)(2 * kk) * S_ + tid,
                                contrib + (size_t)(2 * kk + 1) * S_ + tid);
        sacc = (sacc + v.x) + biasC_s[(2 * kk) * S_ + tid];
        sacc = (sacc + v.y) + biasC_s[(2 * kk + 1) * S_ + tid];
      }
      vec_s[tid] = sacc;
      __syncthreads();
      const float4* s4 = (const float4*)(vec_s + halfc * 128);
      float v0 = 0.f, v1 = 0.f;
      DOTREG_RELU(32, w0, s4, v0);
      v0 += __shfl_down(v0, 1, 2);
      DOTREG_RELU(32, w1, s4, v1);
      v1 += __shfl_down(v1, 1, 2);
      if (halfc == 0)
        st_atomic_f2(mbhid + o_loc,       fmaxf(v0 + bias0, 0.f),
                     mbhid + 128 + o_loc, fmaxf(v1 + bias1, 0.f));
      __syncthreads();
      if (tid == 0) push_flag(outflag, t + 1);
    }

  } else {
    // ============ D: E2 + sampling (r8-exact) ============
    const int o_loc = tid >> 1, halfc = tid & 1;
    const float cf = (float)c_ptr[0];
    float w0[128], w1[128];
    {
      const float* p = e2w + ((size_t)o_loc) * END_ + halfc * 128;
      #pragma unroll
      for (int i = 0; i < 128; ++i) w0[i] = p[i];
      p = e2w + ((size_t)(128 + o_loc)) * END_ + halfc * 128;
      #pragma unroll
      for (int i = 0; i < 128; ++i) w1[i] = p[i];
    }
    const float bias0 = e2b[o_loc], bias1 = e2b[128 + o_loc];
    int* inflag = flags + FID_HID * 16;
    float* logits_s = cond_b_s;  // reuse (unused by D)
    const int lane = tid & 63, wv = tid >> 6;

    for (int t = 0; t < T_; ++t) {
      wave_wait_flag(inflag, t + 1, lane);
      vec_s[tid] = ld_atomic_f(mbhid + tid);
      __syncthreads();
      const float4* h4 = (const float4*)(vec_s + halfc * 128);
      float v0 = 0.f, v1 = 0.f;
      DOTREG(32, w0, h4, v0);
      v0 += __shfl_down(v0, 1, 2);
      DOTREG(32, w1, h4, v1);
      v1 += __shfl_down(v1, 1, 2);
      if (halfc == 0) {
        logits_s[o_loc]       = (v0 + bias0) * cf;
        logits_s[128 + o_loc] = (v1 + bias1) * cf;
      }
      __syncthreads();

      // ---- softmax-CDF sampling over 256 logits (r8 verbatim) ----
      float lg = logits_s[tid];
      float m = lg;
      #pragma unroll
      for (int off = 32; off >= 1; off >>= 1) m = fmaxf(m, __shfl_xor(m, off, 64));
      if (lane == 0) wred[wv] = m;
      __syncthreads();
      m = fmaxf(fmaxf(wred[0], wred[1]), fmaxf(wred[2], wred[3]));
      float e = expf(lg - m);
      float cs = e;
      #pragma unroll
      for (int off = 1; off < 64; off <<= 1) {
        float o_ = __shfl_up(cs, off, 64);
        if (lane >= off) cs += o_;
      }
      if (lane == 63) wsum[wv] = cs;
      __syncthreads();
      float total = wsum[0] + wsum[1] + wsum[2] + wsum[3];
      float offv = 0.f;
      for (int w2 = 0; w2 < wv; ++w2) offv += wsum[w2];
      float thresh = samples[t] * total;
      bool flagb = (offv + cs) > thresh;
      unsigned long long mk = __ballot(flagb);
      if (lane == 0) wcand[wv] = mk ? (wv * 64 + __ffsll(mk) - 1) : 100000;
      __syncthreads();
      if (tid == 0) {
        int nw = min(min(wcand[0], wcand[1]), min(wcand[2], wcand[3]));
        if (nw >= 100000) nw = 0;  // argmax of all-False -> 0
        out[t] = nw;
        push_flag(fprev, ((t + 1) << 16) | nw);
      }
      __syncthreads();  // protect wred/wsum/logits_s before next step
    }
  }
}

extern "C" void kernel_launch(void* const* d_in, const int* in_sizes, int n_in,
                              void* d_out, int out_size, void* d_ws, size_t ws_size,
                              hipStream_t stream) {
  const float* y       = (const float*)d_in[0];
  const float* samples = (const float*)d_in[1];
  const int*   c       = (const int*)d_in[2];
  const float* emb     = (const float*)d_in[3];
  const float* condW   = (const float*)d_in[4];
  const float* WVp     = (const float*)d_in[5];
  const float* WVx     = (const float*)d_in[6];
  const float* Wo      = (const float*)d_in[7];
  const float* Wob     = (const float*)d_in[8];
  const float* Wol     = (const float*)d_in[9];
  const float* Wobl    = (const float*)d_in[10];
  const float* e1w     = (const float*)d_in[11];
  const float* e1b     = (const float*)d_in[12];
  const float* e2w     = (const float*)d_in[13];
  const float* e2b     = (const float*)d_in[14];

  float* ws  = (float*)d_ws;
  int*   out = (int*)d_out;

  // flags + claim counter must start at 0 every launch (ws re-poisoned to 0xAA)
  hipMemsetAsync((char*)d_ws + (size_t)FLAG_OFF * sizeof(float), 0,
                 16 * 16 * sizeof(int), stream);

  cond_prep_kernel<<<(FRAMES_ * L_ * G_ + 255) / 256, 256, 0, stream>>>(
      condW, y, ws + COND8_OFF);

  wavenet_pipe<<<256, 256, 0, stream>>>(samples, c, emb, WVp, WVx, Wo, Wob,
                                        Wol, Wobl, e1w, e1b, e2w, e2b, ws, out);
}

// Round 14
// 8656.016 us; speedup vs baseline: 2.4049x; 1.2832x over previous
//
#include <hip/hip_runtime.h>
#include <cmath>

#define L_     10
#define R_     64
#define G_     128
#define S_     256
#define MEL_   80
#define NCLS_  256
#define HOP_   64
#define END_   256
#define FRAMES_ 8
#define T_     512

typedef unsigned long long u64;

// ---- workspace layout (float offsets; all mailbox offsets 8B-aligned) ----
#define COND8_OFF   0                                // 8*1280
#define HIST_OFF    10240                            // layers 1..8: [(j-1)][512][64]
#define MBX64_OFF   (HIST_OFF + 8*T_*R_)             // u64 x mailboxes [4][64]
#define CTR64_OFF   (MBX64_OFF + 4*R_*2)             // u64 contribs [10][256]
#define HID64_OFF   (CTR64_OFF + 10*S_*2)            // u64 C->D [256]
#define FLAG_OFF    (HID64_OFF + S_*2)               // flags, 16 ints apart

#define FID_PREV   11
#define FID_CLAIM  12

#define NROLE 7
#define SPIN_CAP (1 << 16)

// ====== tagged 64-bit mailbox protocol (XCD-0 pinned) ======
// Slot = (tag<<32)|float_bits, one atomic word: tag and payload can never be
// separated (kills every flag/data ordering hazard of r4-r6 by construction).
// Producer: non-returning swap_x2, fire-and-forget. Consumer: returning
// add_x2(0) — executes at the XCD-0 TCC (r7-proven primitive family), never
// stale. Poisoned slots (0xAAAA...) read as negative tags -> not ready.
__device__ __forceinline__ void push_tag(u64* p, float v, int tag) {
  u64 pk = ((u64)(unsigned)tag << 32) | (unsigned)__float_as_int(v);
  asm volatile("global_atomic_swap_x2 %0, %1, off" :: "v"(p), "v"(pk) : "memory");
}
__device__ __forceinline__ float poll_tag(u64* p, int want) {
  u64 r; int n = 0;
  do {
    asm volatile("global_atomic_add_x2 %0, %1, %2, off sc0\n\ts_waitcnt vmcnt(0)"
                 : "=&v"(r) : "v"(p), "v"(0ULL) : "memory");
    if ((int)(r >> 32) >= want) break;
  } while (++n <= SPIN_CAP);
  return __int_as_float((int)(unsigned)(r & 0xffffffffULL));
}
__device__ __forceinline__ float2 poll_tag2(u64* p0, u64* p1, int want) {
  u64 r0, r1; int n = 0;
  for (;;) {
    asm volatile("global_atomic_add_x2 %0, %2, %4, off sc0\n\t"
                 "global_atomic_add_x2 %1, %3, %4, off sc0\n\t"
                 "s_waitcnt vmcnt(0)"
                 : "=&v"(r0), "=&v"(r1) : "v"(p0), "v"(p1), "v"(0ULL) : "memory");
    if ((int)(r0 >> 32) >= want && (int)(r1 >> 32) >= want) break;
    if (++n > SPIN_CAP) break;
  }
  return make_float2(__int_as_float((int)(unsigned)(r0 & 0xffffffffULL)),
                     __int_as_float((int)(unsigned)(r1 & 0xffffffffULL)));
}
// prev feedback: r8-proven 32-bit packed-tag flag
__device__ __forceinline__ int flag_poll_atomic(int* p) {
  int v;
  asm volatile("global_atomic_add %0, %1, %2, off sc0\n\ts_waitcnt vmcnt(0)"
               : "=&v"(v) : "v"(p), "v"(0) : "memory");
  return v;
}
__device__ __forceinline__ void push_flag(int* p, int v) {
  asm volatile("global_atomic_swap %0, %1, off" :: "v"(p), "v"(v) : "memory");
}
__device__ __forceinline__ int wait_prev_wave(int* p, int want, int lane) {
  int v = 0, n = 0;
  do {
    if (lane == 0) v = flag_poll_atomic(p);
    v = __shfl(v, 0, 64);
    if ((v >> 16) >= want) break;
  } while (++n <= SPIN_CAP);
  return v & 0xffff;
}

// ---- single-chain dot macros: EXACT r8/r13 arithmetic (absmax 0.0 proven).
#define DOTREG(N4, W, V4, ACC) do { \
  _Pragma("unroll") \
  for (int k_ = 0; k_ < (N4); ++k_) { float4 a_ = (V4)[k_]; \
    ACC = fmaf((W)[4*k_+0], a_.x, ACC); ACC = fmaf((W)[4*k_+1], a_.y, ACC); \
    ACC = fmaf((W)[4*k_+2], a_.z, ACC); ACC = fmaf((W)[4*k_+3], a_.w, ACC); } \
} while (0)

#define DOTREG_RELU(N4, W, V4, ACC) do { \
  _Pragma("unroll") \
  for (int k_ = 0; k_ < (N4); ++k_) { float4 a_ = (V4)[k_]; \
    a_.x = fmaxf(a_.x, 0.f); a_.y = fmaxf(a_.y, 0.f); \
    a_.z = fmaxf(a_.z, 0.f); a_.w = fmaxf(a_.w, 0.f); \
    ACC = fmaf((W)[4*k_+0], a_.x, ACC); ACC = fmaf((W)[4*k_+1], a_.y, ACC); \
    ACC = fmaf((W)[4*k_+2], a_.z, ACC); ACC = fmaf((W)[4*k_+3], a_.w, ACC); } \
} while (0)

__global__ void cond_prep_kernel(const float* __restrict__ condW,
                                 const float* __restrict__ y,
                                 float* __restrict__ cond8) {
  int idx = blockIdx.x * blockDim.x + threadIdx.x;
  if (idx >= FRAMES_ * L_ * G_) return;
  int f = idx / (L_ * G_);
  int row = idx - f * (L_ * G_);
  float acc = 0.f;
  for (int m = 0; m < MEL_; ++m)
    acc = fmaf(condW[row * MEL_ + m], y[m * FRAMES_ + f], acc);
  cond8[f * (L_ * G_) + row] = acc;
}

__global__ __launch_bounds__(256, 1) void wavenet_pipe(
    const float* __restrict__ samples,
    const int*   __restrict__ c_ptr,
    const float* __restrict__ emb,
    const float* __restrict__ WVp,
    const float* __restrict__ WVx,
    const float* __restrict__ Wo,
    const float* __restrict__ Wob,
    const float* __restrict__ Wol,
    const float* __restrict__ Wobl,
    const float* __restrict__ e1w,
    const float* __restrict__ e1b,
    const float* __restrict__ e2w,
    const float* __restrict__ e2b,
    float* __restrict__ ws,
    int*   __restrict__ out) {

  const int tid = threadIdx.x;

  float* cond8   = ws + COND8_OFF;
  float* hist    = ws + HIST_OFF;
  u64*   mbx     = (u64*)(ws + MBX64_OFF);
  u64*   contrib = (u64*)(ws + CTR64_OFF);
  u64*   mbhid   = (u64*)(ws + HID64_OFF);
  int*   flags   = (int*)(ws + FLAG_OFF);
  int*   fprev   = flags + FID_PREV * 16;

  __shared__ __align__(16) float x_s[R_];
  __shared__ __align__(16) float xb_s[R_];
  __shared__ __align__(16) float z_s[R_];
  __shared__ __align__(16) float zb_s[R_];
  __shared__ __align__(16) float cond_a_s[FRAMES_ * G_];
  __shared__ __align__(16) float cond_b_s[FRAMES_ * G_];  // D reuses as logits
  __shared__ __align__(16) float biasC_s[10 * S_];        // C only
  __shared__ __align__(16) float vec_s[S_];
  __shared__ float wred[4], wsum[4];
  __shared__ int wcand[4];
  __shared__ int role_s;

  // ---- XCD-pinned role claiming (r7-proven) ----
  {
    unsigned xcc;
    asm volatile("s_getreg_b32 %0, hwreg(HW_REG_XCC_ID)" : "=s"(xcc));
    if (tid == 0) {
      int r = -1;
      if (xcc == 0) {
        int c0 = atomicAdd(flags + FID_CLAIM * 16, 1);
        if (c0 < NROLE) r = c0;
      }
      role_s = r;
    }
    __syncthreads();
  }
  const int bid = role_s;
  if (bid < 0) return;

  if (bid < 5) {
    // ============ B_k: layers j_a=2k, j_b=2k+1 ============
    // fused gate+z (r9-proven) + tagged mailboxes + r13 contribution offload
    const int k = bid;
    const int j_a = 2 * k, j_b = 2 * k + 1;
    const int dil_a = 1 << j_a, dil_b = 1 << j_b;
    const int gr = tid >> 1, gh = tid & 1;

    float wxa_w[32], wxa_f[32], wxb_w[32], wxb_f[32];
    float woa0[64], wob0[64], wex[64];
    float ba0, bb0;
    if (tid < 128) {
      const float4* p;
      p = (const float4*)(WVx + ((size_t)(j_a * G_ + gr)) * R_ + gh * 32);
      #pragma unroll
      for (int i = 0; i < 8; ++i) ((float4*)wxa_w)[i] = p[i];
      p = (const float4*)(WVx + ((size_t)(j_a * G_ + gr + 64)) * R_ + gh * 32);
      #pragma unroll
      for (int i = 0; i < 8; ++i) ((float4*)wxa_f)[i] = p[i];
      p = (const float4*)(WVx + ((size_t)(j_b * G_ + gr)) * R_ + gh * 32);
      #pragma unroll
      for (int i = 0; i < 8; ++i) ((float4*)wxb_w)[i] = p[i];
      p = (const float4*)(WVx + ((size_t)(j_b * G_ + gr + 64)) * R_ + gh * 32);
      #pragma unroll
      for (int i = 0; i < 8; ++i) ((float4*)wxb_f)[i] = p[i];
    }
    {
      const float* q = Wo + ((size_t)(j_a * (R_ + S_) + tid)) * R_;
      #pragma unroll
      for (int i = 0; i < 64; ++i) woa0[i] = q[i];
      ba0 = Wob[j_a * (R_ + S_) + tid];
      if (k < 4) {
        q = Wo + ((size_t)(j_b * (R_ + S_) + tid)) * R_;
        #pragma unroll
        for (int i = 0; i < 64; ++i) wob0[i] = q[i];
        bb0 = Wob[j_b * (R_ + S_) + tid];
      } else {
        q = Wol + (size_t)tid * R_;
        #pragma unroll
        for (int i = 0; i < 64; ++i) wob0[i] = q[i];
        bb0 = 0.f;   // layer-9 bias applied at C
      }
      if (tid < 64) {
        q = Wo + ((size_t)(j_a * (R_ + S_) + 256 + tid)) * R_;
        #pragma unroll
        for (int i = 0; i < 64; ++i) wex[i] = q[i];
      } else if (tid < 128 && k < 4) {
        q = Wo + ((size_t)(j_b * (R_ + S_) + 256 + (tid - 64))) * R_;
        #pragma unroll
        for (int i = 0; i < 64; ++i) wex[i] = q[i];
      }
    }
    for (int i = tid; i < FRAMES_ * G_; i += 256) {
      cond_a_s[i] = cond8[(i >> 7) * (L_ * G_) + j_a * G_ + (i & 127)];
      cond_b_s[i] = cond8[(i >> 7) * (L_ * G_) + j_b * G_ + (i & 127)];
    }
    __syncthreads();
    float pd_aw = 0.f, pd_af = 0.f, pd_bw = 0.f, pd_bf = 0.f;
    if (tid < 128 && gh == 0) {
      pd_aw = cond_a_s[gr]; pd_af = cond_a_s[gr + 64];
      pd_bw = cond_b_s[gr]; pd_bf = cond_b_s[gr + 64];
    }

    float* hist_a = (k > 0) ? (hist + (size_t)(j_a - 1) * T_ * R_) : nullptr;
    float* hist_b = (k < 4) ? (hist + (size_t)(j_b - 1) * T_ * R_) : nullptr;
    u64* mbx_in    = mbx + (size_t)(k - 1) * R_;            // k>=1
    u64* mbx_out   = mbx + (size_t)k * R_;                  // k<4
    u64* contrib_a = contrib + (size_t)j_a * S_;
    u64* contrib_b = contrib + (size_t)j_b * S_;

    for (int t = 0; t < T_; ++t) {
      // A: acquire x — tagged per-lane poll (wave 0)
      if (tid < 64) {
        if (k == 0) {
          int prev = 127;
          if (t > 0) prev = wait_prev_wave(fprev, t, tid);
          if (tid < 16)
            ((float4*)x_s)[tid] = ((const float4*)(emb + (size_t)prev * R_))[tid];
        } else {
          x_s[tid] = poll_tag(mbx_in + tid, t + 1);
        }
      }
      __syncthreads();  // (1) x ready

      // B: fused gate+z layer a (r9-proven, bit-identical h)
      if (tid < 128) {
        const float4* xs4 = (const float4*)(x_s + gh * 32);
        float vw = 0.f, vf = 0.f;
        DOTREG(8, wxa_w, xs4, vw);
        DOTREG(8, wxa_f, xs4, vf);
        vw += __shfl_down(vw, 1, 2);
        vf += __shfl_down(vf, 1, 2);
        if (gh == 0) {
          float hw = vw + pd_aw, hf = vf + pd_af;
          z_s[gr] = tanhf(hw) * (1.f / (1.f + expf(-hf)));
        }
      }
      if (hist_a && tid >= 240)
        ((float4*)(hist_a + (size_t)t * R_))[tid - 240] = ((const float4*)x_s)[tid - 240];
      __syncthreads();  // (2) z_a ready

      // C: residual a (tid<64) + contribution-a dots (r13-exact rows/order)
      float va_keep = 0.f;
      {
        const float4* z4 = (const float4*)z_s;
        if (tid < 64) {
          float v0 = 0.f, v1 = 0.f;
          DOTREG(16, woa0, z4, v0);
          DOTREG(16, wex, z4, v1);
          xb_s[tid] = x_s[tid] + v0 + ba0;
          va_keep = v1;                    // contrib_a row 192+tid
        } else {
          float v0 = 0.f;
          DOTREG(16, woa0, z4, v0);
          va_keep = v0;                    // contrib_a row tid-64
        }
      }
      __syncthreads();  // (3) xb ready

      // D: fused gate+z layer b
      if (tid < 128) {
        const float4* xs4 = (const float4*)(xb_s + gh * 32);
        float vw = 0.f, vf = 0.f;
        DOTREG(8, wxb_w, xs4, vw);
        DOTREG(8, wxb_f, xs4, vf);
        vw += __shfl_down(vw, 1, 2);
        vf += __shfl_down(vf, 1, 2);
        if (gh == 0) {
          float hw = vw + pd_bw, hf = vf + pd_bf;
          zb_s[gr] = tanhf(hw) * (1.f / (1.f + expf(-hf)));
        }
      }
      if (hist_b && tid >= 240)
        ((float4*)(hist_b + (size_t)t * R_))[tid - 240] = ((const float4*)xb_s)[tid - 240];
      __syncthreads();  // (4) z_b ready

      // E: residual b + ALL publishes fire-and-forget (tag carries validity)
      {
        const float4* zb4 = (const float4*)zb_s;
        float v0 = 0.f;
        DOTREG(16, wob0, zb4, v0);
        if (k < 4) {
          if (tid < 64) {
            push_tag(mbx_out + tid, xb_s[tid] + v0 + bb0, t + 1);  // x first
            push_tag(contrib_a + 192 + tid, va_keep, t + 1);
          } else if (tid < 128) {
            float v1 = 0.f;
            DOTREG(16, wex, zb4, v1);
            push_tag(contrib_a + (tid - 64), va_keep, t + 1);
            push_tag(contrib_b + (tid - 64), v0, t + 1);
            push_tag(contrib_b + 192 + (tid - 64), v1, t + 1);
          } else {
            push_tag(contrib_a + (tid - 64), va_keep, t + 1);
            push_tag(contrib_b + (tid - 64), v0, t + 1);
          }
        } else {
          if (tid < 64) {
            push_tag(contrib_b + tid, v0, t + 1);
            push_tag(contrib_a + 192 + tid, va_keep, t + 1);
          } else {
            push_tag(contrib_a + (tid - 64), va_keep, t + 1);
            push_tag(contrib_b + tid, v0, t + 1);
          }
        }
      }

      // F: pd precompute for t+1 (r9-proven: barrier-free, register pd,
      //    streamed WVp slices)
      const int tn = t + 1;
      if (tn < T_ && tid < 128) {
        const int f1 = tn >> 6;
        float wpw[32], wpf[32], pa[32];
        {
          const float4* pw = (const float4*)(WVp + ((size_t)(j_a * G_ + gr)) * R_ + gh * 32);
          const float4* pf = (const float4*)(WVp + ((size_t)(j_a * G_ + gr + 64)) * R_ + gh * 32);
          #pragma unroll
          for (int i = 0; i < 8; ++i) { ((float4*)wpw)[i] = pw[i]; ((float4*)wpf)[i] = pf[i]; }
          if (k == 0) {
            #pragma unroll
            for (int i = 0; i < 8; ++i) ((float4*)pa)[i] = ((const float4*)(x_s + gh * 32))[i];
          } else {
            const int tp = tn - dil_a;
            if (tp >= 0) {
              const float4* hp = (const float4*)(hist_a + (size_t)tp * R_ + gh * 32);
              #pragma unroll
              for (int i = 0; i < 8; ++i) ((float4*)pa)[i] = hp[i];
            } else {
              #pragma unroll
              for (int i = 0; i < 32; ++i) pa[i] = 0.f;
            }
          }
          float vw = 0.f, vf = 0.f;
          const float4* pa4 = (const float4*)pa;
          DOTREG(8, wpw, pa4, vw);
          DOTREG(8, wpf, pa4, vf);
          vw += __shfl_down(vw, 1, 2);
          vf += __shfl_down(vf, 1, 2);
          if (gh == 0) {
            pd_aw = vw + cond_a_s[f1 * G_ + gr];
            pd_af = vf + cond_a_s[f1 * G_ + gr + 64];
          }
        }
        if (k < 4) {
          const float4* pw = (const float4*)(WVp + ((size_t)(j_b * G_ + gr)) * R_ + gh * 32);
          const float4* pf = (const float4*)(WVp + ((size_t)(j_b * G_ + gr + 64)) * R_ + gh * 32);
          #pragma unroll
          for (int i = 0; i < 8; ++i) { ((float4*)wpw)[i] = pw[i]; ((float4*)wpf)[i] = pf[i]; }
          const int tp = tn - dil_b;
          if (tp >= 0) {
            const float4* hp = (const float4*)(hist_b + (size_t)tp * R_ + gh * 32);
            #pragma unroll
            for (int i = 0; i < 8; ++i) ((float4*)pa)[i] = hp[i];
          } else {
            #pragma unroll
            for (int i = 0; i < 32; ++i) pa[i] = 0.f;
          }
          float vw = 0.f, vf = 0.f;
          const float4* pa4 = (const float4*)pa;
          DOTREG(8, wpw, pa4, vw);
          DOTREG(8, wpf, pa4, vf);
          vw += __shfl_down(vw, 1, 2);
          vf += __shfl_down(vf, 1, 2);
          if (gh == 0) {
            pd_bw = vw + cond_b_s[f1 * G_ + gr];
            pd_bf = vf + cond_b_s[f1 * G_ + gr + 64];
          }
        } else {
          if (gh == 0) {
            pd_bw = cond_b_s[f1 * G_ + gr];   // layer 9: past always 0 (dil=512)
            pd_bf = cond_b_s[f1 * G_ + gr + 64];
          }
        }
      }
      __syncthreads();  // (5) LDS buffers reusable at t+1
    }

  } else if (bid == 5) {
    // ============ C: ordered skip fold (r10/r13-proven) + E1 (r8-exact) ======
    const int o_loc = tid >> 1, halfc = tid & 1;
    float w0[128], w1[128];
    {
      const float* p = e1w + ((size_t)o_loc) * S_ + halfc * 128;
      #pragma unroll
      for (int i = 0; i < 128; ++i) w0[i] = p[i];
      p = e1w + ((size_t)(128 + o_loc)) * S_ + halfc * 128;
      #pragma unroll
      for (int i = 0; i < 128; ++i) w1[i] = p[i];
    }
    const float bias0 = e1b[o_loc], bias1 = e1b[128 + o_loc];
    for (int i = tid; i < 10 * S_; i += 256) {
      int j = i >> 8, s = i & 255;
      biasC_s[i] = (j < 9) ? Wob[j * (R_ + S_) + 64 + s] : Wobl[s];
    }
    __syncthreads();

    for (int t = 0; t < T_; ++t) {
      // fold in exact layer order: s = (s + v_j) + b_j  (early pairs arrive
      // long before B4's — only the last poll sits on the critical path)
      float sacc = 0.f;
      for (int kk = 0; kk < 5; ++kk) {
        float2 v = poll_tag2(contrib + (size_t)(2 * kk) * S_ + tid,
                             contrib + (size_t)(2 * kk + 1) * S_ + tid, t + 1);
        sacc = (sacc + v.x) + biasC_s[(2 * kk) * S_ + tid];
        sacc = (sacc + v.y) + biasC_s[(2 * kk + 1) * S_ + tid];
      }
      vec_s[tid] = sacc;
      __syncthreads();
      const float4* s4 = (const float4*)(vec_s + halfc * 128);
      float v0 = 0.f, v1 = 0.f;
      DOTREG_RELU(32, w0, s4, v0);
      v0 += __shfl_down(v0, 1, 2);
      DOTREG_RELU(32, w1, s4, v1);
      v1 += __shfl_down(v1, 1, 2);
      if (halfc == 0) {
        push_tag(mbhid + o_loc,       fmaxf(v0 + bias0, 0.f), t + 1);
        push_tag(mbhid + 128 + o_loc, fmaxf(v1 + bias1, 0.f), t + 1);
      }
      __syncthreads();  // vec_s reuse guard
    }

  } else {
    // ============ D: E2 + sampling (r8-exact) ============
    const int o_loc = tid >> 1, halfc = tid & 1;
    const float cf = (float)c_ptr[0];
    float w0[128], w1[128];
    {
      const float* p = e2w + ((size_t)o_loc) * END_ + halfc * 128;
      #pragma unroll
      for (int i = 0; i < 128; ++i) w0[i] = p[i];
      p = e2w + ((size_t)(128 + o_loc)) * END_ + halfc * 128;
      #pragma unroll
      for (int i = 0; i < 128; ++i) w1[i] = p[i];
    }
    const float bias0 = e2b[o_loc], bias1 = e2b[128 + o_loc];
    float* logits_s = cond_b_s;  // reuse (unused by D)
    const int lane = tid & 63, wv = tid >> 6;

    for (int t = 0; t < T_; ++t) {
      vec_s[tid] = poll_tag(mbhid + tid, t + 1);
      __syncthreads();
      const float4* h4 = (const float4*)(vec_s + halfc * 128);
      float v0 = 0.f, v1 = 0.f;
      DOTREG(32, w0, h4, v0);
      v0 += __shfl_down(v0, 1, 2);
      DOTREG(32, w1, h4, v1);
      v1 += __shfl_down(v1, 1, 2);
      if (halfc == 0) {
        logits_s[o_loc]       = (v0 + bias0) * cf;
        logits_s[128 + o_loc] = (v1 + bias1) * cf;
      }
      __syncthreads();

      // ---- softmax-CDF sampling over 256 logits (r8 verbatim) ----
      float lg = logits_s[tid];
      float m = lg;
      #pragma unroll
      for (int off = 32; off >= 1; off >>= 1) m = fmaxf(m, __shfl_xor(m, off, 64));
      if (lane == 0) wred[wv] = m;
      __syncthreads();
      m = fmaxf(fmaxf(wred[0], wred[1]), fmaxf(wred[2], wred[3]));
      float e = expf(lg - m);
      float cs = e;
      #pragma unroll
      for (int off = 1; off < 64; off <<= 1) {
        float o_ = __shfl_up(cs, off, 64);
        if (lane >= off) cs += o_;
      }
      if (lane == 63) wsum[wv] = cs;
      __syncthreads();
      float total = wsum[0] + wsum[1] + wsum[2] + wsum[3];
      float offv = 0.f;
      for (int w2 = 0; w2 < wv; ++w2) offv += wsum[w2];
      float thresh = samples[t] * total;
      bool flagb = (offv + cs) > thresh;
      unsigned long long mk = __ballot(flagb);
      if (lane == 0) wcand[wv] = mk ? (wv * 64 + __ffsll(mk) - 1) : 100000;
      __syncthreads();
      if (tid == 0) {
        int nw = min(min(wcand[0], wcand[1]), min(wcand[2], wcand[3]));
        if (nw >= 100000) nw = 0;  // argmax of all-False -> 0
        out[t] = nw;
        push_flag(fprev, ((t + 1) << 16) | nw);
      }
      __syncthreads();  // protect wred/wsum/logits_s before next step
    }
  }
}

extern "C" void kernel_launch(void* const* d_in, const int* in_sizes, int n_in,
                              void* d_out, int out_size, void* d_ws, size_t ws_size,
                              hipStream_t stream) {
  const float* y       = (const float*)d_in[0];
  const float* samples = (const float*)d_in[1];
  const int*   c       = (const int*)d_in[2];
  const float* emb     = (const float*)d_in[3];
  const float* condW   = (const float*)d_in[4];
  const float* WVp     = (const float*)d_in[5];
  const float* WVx     = (const float*)d_in[6];
  const float* Wo      = (const float*)d_in[7];
  const float* Wob     = (const float*)d_in[8];
  const float* Wol     = (const float*)d_in[9];
  const float* Wobl    = (const float*)d_in[10];
  const float* e1w     = (const float*)d_in[11];
  const float* e1b     = (const float*)d_in[12];
  const float* e2w     = (const float*)d_in[13];
  const float* e2b     = (const float*)d_in[14];

  float* ws  = (float*)d_ws;
  int*   out = (int*)d_out;

  // Only flags need zeroing; mailbox tags rely on the 0xAA poison reading as
  // negative (never >= any t+1). Harness re-poisons ws before every launch.
  hipMemsetAsync((char*)d_ws + (size_t)FLAG_OFF * sizeof(float), 0,
                 16 * 16 * sizeof(int), stream);

  cond_prep_kernel<<<(FRAMES_ * L_ * G_ + 255) / 256, 256, 0, stream>>>(
      condW, y, ws + COND8_OFF);

  wavenet_pipe<<<256, 256, 0, stream>>>(samples, c, emb, WVp, WVx, Wo, Wob,
                                        Wol, Wobl, e1w, e1b, e2w, e2b, ws, out);
}